// Round 4
// baseline (387.072 us; speedup 1.0000x reference)
//
#include <hip/hip_runtime.h>
#include <math.h>

// XMIX mixing network — split-bf16 MFMA, pipelined weight streams.
// TB=32 samples/block, 1024 blocks x 512 threads, LDS 80KB -> 2 blocks/CU.
// R4: P3 split into two passes with explicit 2-deep ping-pong on B-fragments
// (sized to fit 128 VGPR so the compiler keeps loads in flight), P4 ping-pong
// + issue-early prefetch across barriers, w1 epilogue layout a*33 (de-conflict).

#define NB 32768
#define TB 32
#define THREADS 512
#define NBLOCKS (NB / TB)   // 1024

typedef short sh8 __attribute__((ext_vector_type(8)));  // 8 bf16 (4 VGPR)
typedef float f4 __attribute__((ext_vector_type(4)));   // MFMA C/D
typedef unsigned short ush;

// ---- workspace layout (ushort units). WT[col][k] hi/lo planes ----
#define OFF_WCAT_H 0                        // [640][512]  (W1a|Wfa|Wb1|Wv1|pad)
#define OFF_WCAT_L (640 * 512)
#define OFF_W1B_H  (2 * 640 * 512)          // [256][256]
#define OFF_W1B_L  (OFF_W1B_H + 256 * 256)
#define OFF_WFB_H  (OFF_W1B_L + 256 * 256)  // [32][256]
#define OFF_WFB_L  (OFF_WFB_H + 32 * 256)
#define OFF_TOK_H  (OFF_WFB_L + 32 * 256)   // [32][64]
#define OFF_TOK_L  (OFF_TOK_H + 32 * 64)
#define OFF_YFC_H  (OFF_TOK_L + 32 * 64)    // [64][32]
#define OFF_YFC_L  (OFF_YFC_H + 64 * 32)
// total shorts = 811008 (1.62 MB of d_ws)

__device__ __forceinline__ ush f2bf(float x) {
    unsigned u = __float_as_uint(x);
    u += 0x7fffu + ((u >> 16) & 1u);        // RNE
    return (ush)(u >> 16);
}
__device__ __forceinline__ float bf2f(ush h) {
    return __uint_as_float(((unsigned)h) << 16);
}
__device__ __forceinline__ void splitbf(float x, ush& h, ush& l) {
    h = f2bf(x);
    l = f2bf(x - bf2f(h));
}
__device__ __forceinline__ f4 mfma(sh8 a, sh8 b, f4 c) {
    return __builtin_amdgcn_mfma_f32_16x16x32_bf16(a, b, c, 0, 0, 0);
}
__device__ __forceinline__ void split8(const float4 v0, const float4 v1, sh8& Ah, sh8& Al) {
    ush h, l;
    splitbf(v0.x, h, l); Ah[0] = (short)h; Al[0] = (short)l;
    splitbf(v0.y, h, l); Ah[1] = (short)h; Al[1] = (short)l;
    splitbf(v0.z, h, l); Ah[2] = (short)h; Al[2] = (short)l;
    splitbf(v0.w, h, l); Ah[3] = (short)h; Al[3] = (short)l;
    splitbf(v1.x, h, l); Ah[4] = (short)h; Al[4] = (short)l;
    splitbf(v1.y, h, l); Ah[5] = (short)h; Al[5] = (short)l;
    splitbf(v1.z, h, l); Ah[6] = (short)h; Al[6] = (short)l;
    splitbf(v1.w, h, l); Ah[7] = (short)h; Al[7] = (short)l;
}

// LDS swizzles (write and read use the same bijection).
__device__ __forceinline__ unsigned swY(unsigned a) {   // 1024B-stride sample rows
    return a ^ (((((a >> 10) & 7) ^ ((a >> 7) & 7)) << 4));
}
__device__ __forceinline__ unsigned swH(unsigned a) {   // 512B-stride rows
    return a ^ (((a >> 9) & 7) << 4);
}
__device__ __forceinline__ unsigned swS(unsigned a) {   // 64B-stride scratch
    return a ^ (((a >> 7) & 3) << 4);
}

// ---------------- prep: LDS-tiled transpose + hi/lo split ----------------
// src must already point at the first source row of this K-tile.
__device__ void tileT(const float* src, int snc, int scol0, int ncol, int nk,
                      ush* dH, ush* dL, int dstride, float (*T)[68])
{
    const int tid = threadIdx.x;
    const int nc4 = ncol >> 2;
    const int s_r = (nc4 == 16) ? 4 : 3;
    const int items_r = nk * nc4;
    for (int i = tid; i < items_r; i += 256) {
        const int r = i >> s_r, c4 = i & (nc4 - 1);
        const float4 v = *(const float4*)(src + r * snc + scol0 + c4 * 4);
        T[r][c4 * 4 + 0] = v.x; T[r][c4 * 4 + 1] = v.y;
        T[r][c4 * 4 + 2] = v.z; T[r][c4 * 4 + 3] = v.w;
    }
    __syncthreads();
    const int nk4 = nk >> 2;
    const int s_w = (nk4 == 16) ? 4 : 3;
    const int items_w = ncol * nk4;
    for (int i = tid; i < items_w; i += 256) {
        const int c = i >> s_w, kq = i & (nk4 - 1);
        ushort4 hv, lv;
        ush h, lo;
        splitbf(T[kq * 4 + 0][c], h, lo); hv.x = h; lv.x = lo;
        splitbf(T[kq * 4 + 1][c], h, lo); hv.y = h; lv.y = lo;
        splitbf(T[kq * 4 + 2][c], h, lo); hv.z = h; lv.z = lo;
        splitbf(T[kq * 4 + 3][c], h, lo); hv.w = h; lv.w = lo;
        *(ushort4*)(dH + c * dstride + kq * 4) = hv;
        *(ushort4*)(dL + c * dstride + kq * 4) = lv;
    }
    __syncthreads();
}

__global__ __launch_bounds__(256) void xmix_prep(
    const float* __restrict__ W_tok, const float* __restrict__ W_yfc,
    const float* __restrict__ W1a, const float* __restrict__ W1b,
    const float* __restrict__ Wfa, const float* __restrict__ Wfb,
    const float* __restrict__ Wb1, const float* __restrict__ Wv1,
    ush* __restrict__ ws)
{
    __shared__ float T[64][68];
    const int b = blockIdx.x;
    if (b < 80) {                    // Wcat [512 k][640 col]
        const int kt = b / 10, ct = b % 10;
        const int k0 = kt * 64;
        if (ct < 4) {
            tileT(W1a + (size_t)k0 * 256, 256, ct * 64, 64, 64,
                  ws + OFF_WCAT_H + (ct * 64) * 512 + k0,
                  ws + OFF_WCAT_L + (ct * 64) * 512 + k0, 512, T);
        } else if (ct < 8) {
            tileT(Wfa + (size_t)k0 * 256, 256, (ct - 4) * 64, 64, 64,
                  ws + OFF_WCAT_H + (ct * 64) * 512 + k0,
                  ws + OFF_WCAT_L + (ct * 64) * 512 + k0, 512, T);
        } else if (ct == 8) {
            tileT(Wb1 + (size_t)k0 * 32, 32, 0, 32, 64,
                  ws + OFF_WCAT_H + 512 * 512 + k0,
                  ws + OFF_WCAT_L + 512 * 512 + k0, 512, T);
            tileT(Wv1 + (size_t)k0 * 32, 32, 0, 32, 64,
                  ws + OFF_WCAT_H + 544 * 512 + k0,
                  ws + OFF_WCAT_L + 544 * 512 + k0, 512, T);
        } else {                     // zero pad cols 576..639
            const int tid = threadIdx.x;
            const ushort4 z = {0, 0, 0, 0};
            for (int i = tid; i < 64 * 16; i += 256) {
                const int c = i >> 4, kq = i & 15;
                *(ushort4*)(ws + OFF_WCAT_H + (576 + c) * 512 + k0 + kq * 4) = z;
                *(ushort4*)(ws + OFF_WCAT_L + (576 + c) * 512 + k0 + kq * 4) = z;
            }
        }
    } else if (b < 96) {             // W1b [256][256]
        const int i = b - 80, kt = i >> 2, ct = i & 3;
        tileT(W1b + (size_t)(kt * 64) * 256, 256, ct * 64, 64, 64,
              ws + OFF_W1B_H + (ct * 64) * 256 + kt * 64,
              ws + OFF_W1B_L + (ct * 64) * 256 + kt * 64, 256, T);
    } else if (b < 100) {            // Wfb [256][32]
        const int kt = b - 96;
        tileT(Wfb + (size_t)(kt * 64) * 32, 32, 0, 32, 64,
              ws + OFF_WFB_H + kt * 64,
              ws + OFF_WFB_L + kt * 64, 256, T);
    } else if (b == 100) {           // W_tok [64][32]
        tileT(W_tok, 32, 0, 32, 64, ws + OFF_TOK_H, ws + OFF_TOK_L, 64, T);
    } else {                         // W_yfc [32][64]
        tileT(W_yfc, 64, 0, 64, 32, ws + OFF_YFC_H, ws + OFF_YFC_L, 32, T);
    }
}

// ---------------- main fused kernel ----------------
__global__ __launch_bounds__(THREADS, 4) void xmix_mfma(
    const float* __restrict__ agent_qs,
    const float* __restrict__ states,
    const ush* __restrict__ ws,
    const float* __restrict__ b_tok, const float* __restrict__ b_yfc,
    const float* __restrict__ b1a,  const float* __restrict__ b1b,
    const float* __restrict__ bfa,  const float* __restrict__ bfb,
    const float* __restrict__ bb1,  const float* __restrict__ bv1,
    const float* __restrict__ Wv2,  const float* __restrict__ bv2,
    float* __restrict__ out)
{
    // BB phases:
    //  (1) Y-split bf16: hi [32][512] @0 (32KB), lo @32768
    //  (2) H1-hi @0 (16KB), H1-lo @16384, HF-hi @32768, HF-lo @49152
    //  (3) w1 f32 [32][264] (a*33+e) @0 (33792), wf [32][36] @33792,
    //      hidden [32][36] @38400, tprod @43008  (end 47616)
    __shared__ __align__(16) unsigned char BBs[65536];
    // SM: e-scratch (P1/P2: 2KB/wave) -> b1 f32 [32][36] @0, v1 @4608
    __shared__ __align__(16) unsigned char SMs[16384];

    const int tid = threadIdx.x;
    const int wv = tid >> 6;          // wave 0..7
    const int l   = tid & 63;
    const int l16 = l & 15;
    const int lq  = l >> 4;
    const int base = blockIdx.x * TB;
    const f4 fzero = {0.f, 0.f, 0.f, 0.f};

    // ---- P1+P2: e = relu(s@W_tok+b) ; y = relu(e@W_yfc+b) -> Y-split in BB ----
    {
        const ush* tokH = ws + OFF_TOK_H;
        const ush* tokL = ws + OFF_TOK_L;
        const ush* yfcH = ws + OFF_YFC_H;
        const ush* yfcL = ws + OFF_YFC_L;
        unsigned char* scr = &SMs[wv * 2048];   // e-split: hi[16][32] @0, lo @1024

        float btok[2];
        btok[0] = b_tok[l16]; btok[1] = b_tok[16 + l16];
        float byfc[4];
        #pragma unroll
        for (int n = 0; n < 4; n++) byfc[n] = b_yfc[n * 16 + l16];

        sh8 TBh[2][2], TBl[2][2];
        #pragma unroll
        for (int n = 0; n < 2; n++)
            #pragma unroll
            for (int kc = 0; kc < 2; kc++) {
                const int coff = (n * 16 + l16) * 64 + kc * 32 + lq * 8;
                TBh[n][kc] = *(const sh8*)(tokH + coff);
                TBl[n][kc] = *(const sh8*)(tokL + coff);
            }
        sh8 YBh[4], YBl[4];
        #pragma unroll
        for (int n = 0; n < 4; n++) {
            const int coff = (n * 16 + l16) * 32 + lq * 8;
            YBh[n] = *(const sh8*)(yfcH + coff);
            YBl[n] = *(const sh8*)(yfcL + coff);
        }

        #pragma unroll
        for (int i = 0; i < 2; i++) {
            const int rt = wv * 2 + i;                 // e-row tile (0..15)
            const int r = rt * 16 + l16;               // agent-row 0..255
            const float* srow = states + (size_t)(base + (r >> 3)) * 512 + (r & 7) * 64;
            f4 eacc[2] = {fzero, fzero};
            #pragma unroll
            for (int kc = 0; kc < 2; kc++) {
                const float4 v0 = *(const float4*)(srow + kc * 32 + lq * 8);
                const float4 v1 = *(const float4*)(srow + kc * 32 + lq * 8 + 4);
                sh8 Ah, Al;
                split8(v0, v1, Ah, Al);
                #pragma unroll
                for (int n = 0; n < 2; n++) {
                    eacc[n] = mfma(Ah, TBh[n][kc], eacc[n]);
                    eacc[n] = mfma(Ah, TBl[n][kc], eacc[n]);
                    eacc[n] = mfma(Al, TBh[n][kc], eacc[n]);
                }
            }
            // e -> per-wave scratch (split, swizzled)
            #pragma unroll
            for (int n = 0; n < 2; n++)
                #pragma unroll
                for (int j = 0; j < 4; j++) {
                    const float e = fmaxf(eacc[n][j] + btok[n], 0.f);
                    const unsigned sa = swS((unsigned)((lq * 4 + j) * 64 + (n * 16 + l16) * 2));
                    ush hh, ll; splitbf(e, hh, ll);
                    *(ush*)(scr + sa)        = hh;
                    *(ush*)(scr + 1024 + sa) = ll;
                }
            // P2: y-tile = e-tile @ W_yfc
            f4 yacc[4] = {fzero, fzero, fzero, fzero};
            {
                const unsigned sa = swS((unsigned)(l16 * 64 + lq * 16));
                const sh8 Ah = *(const sh8*)(scr + sa);
                const sh8 Al = *(const sh8*)(scr + 1024 + sa);
                #pragma unroll
                for (int n = 0; n < 4; n++) {
                    yacc[n] = mfma(Ah, YBh[n], yacc[n]);
                    yacc[n] = mfma(Ah, YBl[n], yacc[n]);
                    yacc[n] = mfma(Al, YBh[n], yacc[n]);
                }
            }
            // y -> Y-split planes
            #pragma unroll
            for (int n = 0; n < 4; n++)
                #pragma unroll
                for (int j = 0; j < 4; j++) {
                    const float y = fmaxf(yacc[n][j] + byfc[n], 0.f);
                    const int rr = rt * 16 + lq * 4 + j;   // agent-row
                    const int ff = n * 16 + l16;
                    const unsigned sa = swY((unsigned)(rr * 128 + ff * 2));
                    ush hh, ll; splitbf(y, hh, ll);
                    *(ush*)(&BBs[sa])         = hh;
                    *(ush*)(&BBs[32768 + sa]) = ll;
                }
        }
    }

    // ---- P3: Y[32,512] @ Wcat[512,640], two passes, 2-deep ping-pong ----
    const ush* wcH = ws + OFF_WCAT_H;
    const ush* wcL = ws + OFF_WCAT_L;
    const int cbA0 = ((wv * 5 + 0) * 16 + l16) * 512;
    const int cbA1 = ((wv * 5 + 1) * 16 + l16) * 512;
    const int cbA2 = ((wv * 5 + 2) * 16 + l16) * 512;
    const int cbB0 = ((wv * 5 + 3) * 16 + l16) * 512;
    const int cbB1 = ((wv * 5 + 4) * 16 + l16) * 512;
    const int rowb0 = l16 * 1024;
    const int rowb1 = (16 + l16) * 1024;

    f4 accA[2][3], accB[2][2];
    #pragma unroll
    for (int m = 0; m < 2; m++) {
        #pragma unroll
        for (int t = 0; t < 3; t++) accA[m][t] = fzero;
        accB[m][0] = fzero; accB[m][1] = fzero;
    }

#define LDA3(BH, BL, KC) { const int ko_ = (KC) * 32 + lq * 8; \
    BH[0] = *(const sh8*)(wcH + cbA0 + ko_); \
    BH[1] = *(const sh8*)(wcH + cbA1 + ko_); \
    BH[2] = *(const sh8*)(wcH + cbA2 + ko_); \
    BL[0] = *(const sh8*)(wcL + cbA0 + ko_); \
    BL[1] = *(const sh8*)(wcL + cbA1 + ko_); \
    BL[2] = *(const sh8*)(wcL + cbA2 + ko_); }

#define MMA3(BH, BL, KC) { const int ko_ = (KC) * 32 + lq * 8; \
    const unsigned sa0_ = swY((unsigned)(rowb0 + ko_ * 2)); \
    const unsigned sa1_ = swY((unsigned)(rowb1 + ko_ * 2)); \
    const sh8 Ah0_ = *(const sh8*)(&BBs[sa0_]); \
    const sh8 Al0_ = *(const sh8*)(&BBs[32768 + sa0_]); \
    const sh8 Ah1_ = *(const sh8*)(&BBs[sa1_]); \
    const sh8 Al1_ = *(const sh8*)(&BBs[32768 + sa1_]); \
    _Pragma("unroll") \
    for (int t = 0; t < 3; t++) { \
        accA[0][t] = mfma(Ah0_, BH[t], accA[0][t]); \
        accA[1][t] = mfma(Ah1_, BH[t], accA[1][t]); } \
    _Pragma("unroll") \
    for (int t = 0; t < 3; t++) { \
        accA[0][t] = mfma(Al0_, BH[t], accA[0][t]); \
        accA[1][t] = mfma(Al1_, BH[t], accA[1][t]); } \
    _Pragma("unroll") \
    for (int t = 0; t < 3; t++) { \
        accA[0][t] = mfma(Ah0_, BL[t], accA[0][t]); \
        accA[1][t] = mfma(Ah1_, BL[t], accA[1][t]); } }

#define LDB2(BH, BL, KC) { const int ko_ = (KC) * 32 + lq * 8; \
    BH[0] = *(const sh8*)(wcH + cbB0 + ko_); \
    BH[1] = *(const sh8*)(wcH + cbB1 + ko_); \
    BL[0] = *(const sh8*)(wcL + cbB0 + ko_); \
    BL[1] = *(const sh8*)(wcL + cbB1 + ko_); }

#define MMB2(BH, BL, KC) { const int ko_ = (KC) * 32 + lq * 8; \
    const unsigned sa0_ = swY((unsigned)(rowb0 + ko_ * 2)); \
    const unsigned sa1_ = swY((unsigned)(rowb1 + ko_ * 2)); \
    const sh8 Ah0_ = *(const sh8*)(&BBs[sa0_]); \
    const sh8 Al0_ = *(const sh8*)(&BBs[32768 + sa0_]); \
    const sh8 Ah1_ = *(const sh8*)(&BBs[sa1_]); \
    const sh8 Al1_ = *(const sh8*)(&BBs[32768 + sa1_]); \
    _Pragma("unroll") \
    for (int t = 0; t < 2; t++) { \
        accB[0][t] = mfma(Ah0_, BH[t], accB[0][t]); \
        accB[1][t] = mfma(Ah1_, BH[t], accB[1][t]); } \
    _Pragma("unroll") \
    for (int t = 0; t < 2; t++) { \
        accB[0][t] = mfma(Al0_, BH[t], accB[0][t]); \
        accB[1][t] = mfma(Al1_, BH[t], accB[1][t]); } \
    _Pragma("unroll") \
    for (int t = 0; t < 2; t++) { \
        accB[0][t] = mfma(Ah0_, BL[t], accB[0][t]); \
        accB[1][t] = mfma(Ah1_, BL[t], accB[1][t]); } }

    sh8 XH[3], XL[3], YH[3], YL[3];
    LDA3(XH, XL, 0);        // issued before the barrier: overlaps barrier drain
    __syncthreads();        // Y-split visible to all waves

    // pass A: t = 0..2
    #pragma unroll 1
    for (int kc2 = 0; kc2 < 8; kc2++) {
        LDA3(YH, YL, 2 * kc2 + 1);
        MMA3(XH, XL, 2 * kc2);
        LDA3(XH, XL, 2 * kc2 + 2);   // kc=16 overshoot reads in-bounds garbage, unused
        MMA3(YH, YL, 2 * kc2 + 1);
    }
    // pass B: t = 3..4
    {
        sh8 ZH0[2], ZL0[2], ZH1[2], ZL1[2];
        LDB2(ZH0, ZL0, 0);
        #pragma unroll 1
        for (int kc2 = 0; kc2 < 8; kc2++) {
            LDB2(ZH1, ZL1, 2 * kc2 + 1);
            MMB2(ZH0, ZL0, 2 * kc2);
            LDB2(ZH0, ZL0, 2 * kc2 + 2);   // overshoot safe
            MMB2(ZH1, ZL1, 2 * kc2 + 1);
        }
    }

    // ---- P4 prefetch (global weights only; independent of barriers) ----
    const ush* w1H = ws + OFF_W1B_H;
    const ush* w1L = ws + OFF_W1B_L;
    const ush* wfH = ws + OFF_WFB_H;
    const ush* wfL = ws + OFF_WFB_L;
    const int cb0 = ((wv * 2 + 0) * 16 + l16) * 256;
    const int cb1 = ((wv * 2 + 1) * 16 + l16) * 256;
    const int mw = wv & 1, nw = (wv >> 1) & 1;
    const int cbw = (nw * 16 + l16) * 256;
    const bool dowf = (wv < 4);

    sh8 P0h[2], P0l[2], P1h[2], P1l[2];
    sh8 Q0h, Q0l, Q1h, Q1l;

#define LDP4(BH, BL, WH, WL, KC) { const int ko_ = (KC) * 32 + lq * 8; \
    BH[0] = *(const sh8*)(w1H + cb0 + ko_); \
    BH[1] = *(const sh8*)(w1H + cb1 + ko_); \
    BL[0] = *(const sh8*)(w1L + cb0 + ko_); \
    BL[1] = *(const sh8*)(w1L + cb1 + ko_); \
    if (dowf) { WH = *(const sh8*)(wfH + cbw + ko_); \
                WL = *(const sh8*)(wfL + cbw + ko_); } }

    LDP4(P0h, P0l, Q0h, Q0l, 0);   // in flight across both barriers below

    __syncthreads();   // all waves done reading Y

    // ---- P3 epilogue: acc -> H1-split / HF-split / b1 / v1 ----
    {
        #pragma unroll
        for (int t = 0; t < 5; t++) {
            const int gt = wv * 5 + t;
            const int cg = gt * 16 + l16;
            f4 av[2];
            av[0] = (t < 3) ? accA[0][t] : accB[0][t - 3];
            av[1] = (t < 3) ? accA[1][t] : accB[1][t - 3];
            if (gt < 16) {                       // H1 = relu(y@W1a + b1a)
                const float bias = b1a[cg];
                #pragma unroll
                for (int m = 0; m < 2; m++)
                    #pragma unroll
                    for (int j = 0; j < 4; j++) {
                        const int row = m * 16 + lq * 4 + j;
                        const float h = fmaxf(av[m][j] + bias, 0.f);
                        ush hh, ll; splitbf(h, hh, ll);
                        const unsigned sa = swH((unsigned)(row * 512 + cg * 2));
                        *(ush*)(&BBs[sa])         = hh;
                        *(ush*)(&BBs[16384 + sa]) = ll;
                    }
            } else if (gt < 32) {                // HF = relu(y@Wfa + bfa)
                const int c = cg - 256;
                const float bias = bfa[c];
                #pragma unroll
                for (int m = 0; m < 2; m++)
                    #pragma unroll
                    for (int j = 0; j < 4; j++) {
                        const int row = m * 16 + lq * 4 + j;
                        const float h = fmaxf(av[m][j] + bias, 0.f);
                        ush hh, ll; splitbf(h, hh, ll);
                        const unsigned sa = swH((unsigned)(row * 512 + c * 2));
                        *(ush*)(&BBs[32768 + sa]) = hh;
                        *(ush*)(&BBs[49152 + sa]) = ll;
                    }
            } else if (gt < 34) {                // b1 = y@Wb1 + bb1 (no relu)
                const int c = cg - 512;
                const float bias = bb1[c];
                #pragma unroll
                for (int m = 0; m < 2; m++)
                    #pragma unroll
                    for (int j = 0; j < 4; j++) {
                        const int row = m * 16 + lq * 4 + j;
                        *(float*)(&SMs[(row * 36 + c) * 4]) = av[m][j] + bias;
                    }
            } else if (gt < 36) {                // v1 = relu(y@Wv1 + bv1)
                const int c = cg - 544;
                const float bias = bv1[c];
                #pragma unroll
                for (int m = 0; m < 2; m++)
                    #pragma unroll
                    for (int j = 0; j < 4; j++) {
                        const int row = m * 16 + lq * 4 + j;
                        *(float*)(&SMs[4608 + (row * 36 + c) * 4]) =
                            fmaxf(av[m][j] + bias, 0.f);
                    }
            } // gt>=36: pad, discard
        }
    }
    __syncthreads();

    // ---- P4: w1 = |H1@W1b + b1b| ; wf = |HF@Wfb + bfb| (2-deep ping-pong) ----
    f4 acc4[2][2];
    #pragma unroll
    for (int m = 0; m < 2; m++) { acc4[m][0] = fzero; acc4[m][1] = fzero; }
    f4 accw = fzero;

#define MMP4(BH, BL, WH, WL, KC) { const int ko_ = (KC) * 32 + lq * 8; \
    const unsigned sa0_ = swH((unsigned)(l16 * 512 + ko_ * 2)); \
    const unsigned sa1_ = swH((unsigned)((16 + l16) * 512 + ko_ * 2)); \
    const sh8 Ah0_ = *(const sh8*)(&BBs[sa0_]); \
    const sh8 Al0_ = *(const sh8*)(&BBs[16384 + sa0_]); \
    const sh8 Ah1_ = *(const sh8*)(&BBs[sa1_]); \
    const sh8 Al1_ = *(const sh8*)(&BBs[16384 + sa1_]); \
    acc4[0][0] = mfma(Ah0_, BH[0], acc4[0][0]); \
    acc4[1][0] = mfma(Ah1_, BH[0], acc4[1][0]); \
    acc4[0][1] = mfma(Ah0_, BH[1], acc4[0][1]); \
    acc4[1][1] = mfma(Ah1_, BH[1], acc4[1][1]); \
    acc4[0][0] = mfma(Al0_, BH[0], acc4[0][0]); \
    acc4[1][0] = mfma(Al1_, BH[0], acc4[1][0]); \
    acc4[0][1] = mfma(Al0_, BH[1], acc4[0][1]); \
    acc4[1][1] = mfma(Al1_, BH[1], acc4[1][1]); \
    acc4[0][0] = mfma(Ah0_, BL[0], acc4[0][0]); \
    acc4[1][0] = mfma(Ah1_, BL[0], acc4[1][0]); \
    acc4[0][1] = mfma(Ah0_, BL[1], acc4[0][1]); \
    acc4[1][1] = mfma(Ah1_, BL[1], acc4[1][1]); \
    if (dowf) { \
        const unsigned saw_ = swH((unsigned)((mw * 16 + l16) * 512 + ko_ * 2)); \
        const sh8 Awh_ = *(const sh8*)(&BBs[32768 + saw_]); \
        const sh8 Awl_ = *(const sh8*)(&BBs[49152 + saw_]); \
        accw = mfma(Awh_, WH, accw); \
        accw = mfma(Awl_, WH, accw); \
        accw = mfma(Awh_, WL, accw); } }

    #pragma unroll 1
    for (int kc2 = 0; kc2 < 4; kc2++) {
        LDP4(P1h, P1l, Q1h, Q1l, 2 * kc2 + 1);
        MMP4(P0h, P0l, Q0h, Q0l, 2 * kc2);
        LDP4(P0h, P0l, Q0h, Q0l, 2 * kc2 + 2);   // kc=8 overshoot safe
        MMP4(P1h, P1l, Q1h, Q1l, 2 * kc2 + 1);
    }
    __syncthreads();   // H1/HF consumed

    // w1/wf -> f32 LDS.  w1 layout [s][a*33+e] (row stride 264) de-conflicts P5.
    {
        #pragma unroll
        for (int t = 0; t < 2; t++) {
            const int col = (wv * 2 + t) * 16 + l16;
            const int a = col >> 5, e = col & 31;
            const float bias = b1b[col];
            #pragma unroll
            for (int m = 0; m < 2; m++)
                #pragma unroll
                for (int j = 0; j < 4; j++) {
                    const int row = m * 16 + lq * 4 + j;
                    *(float*)(&BBs[(row * 264 + a * 33 + e) * 4]) =
                        fabsf(acc4[m][t][j] + bias);
                }
        }
        if (dowf) {
            const int col = nw * 16 + l16;
            const float bias = bfb[col];
            #pragma unroll
            for (int j = 0; j < 4; j++) {
                const int row = mw * 16 + lq * 4 + j;
                *(float*)(&BBs[33792 + (row * 36 + col) * 4]) =
                    fabsf(accw[j] + bias);
            }
        }
    }
    __syncthreads();

    // ---- P5: epilogue (elu, delu, q_tot, grad) ----
    {
        const int s = tid >> 4, li = tid & 15;
        const int b = base + s;
        float q[8];
        #pragma unroll
        for (int a = 0; a < 8; a++) q[a] = agent_qs[(size_t)b * 8 + a];
        const float* w1p = (const float*)(&BBs[0]);        // [32][264], a*33+e
        const float* wfp = (const float*)(&BBs[33792]);    // [32][36]
        const float* b1p = (const float*)(&SMs[0]);        // [32][36]
        float* hidp = (float*)(&BBs[38400]);
        float* tpp  = (float*)(&BBs[43008]);
        #pragma unroll
        for (int ii = 0; ii < 2; ii++) {
            const int e = li + 16 * ii;
            float z = b1p[s * 36 + e];
            #pragma unroll
            for (int a = 0; a < 8; a++) z = fmaf(q[a], w1p[s * 264 + a * 33 + e], z);
            const float h = (z > 0.f) ? z : (expf(z) - 1.f);   // elu
            const float d = (h < 0.f) ? expf(h) : 1.f;          // delu of elu OUTPUT (ref!)
            hidp[s * 36 + e] = h;
            tpp[s * 36 + e] = d * wfp[s * 36 + e];
        }
    }
    __syncthreads();
    {
        const float* w1p = (const float*)(&BBs[0]);
        const float* wfp = (const float*)(&BBs[33792]);
        const float* v1p = (const float*)(&SMs[4608]);
        const float* hidp = (const float*)(&BBs[38400]);
        const float* tpp  = (const float*)(&BBs[43008]);
        if (tid < 256) {
            const int s = tid >> 3, a = tid & 7;
            const int b = base + s;
            float g = 0.f;
            #pragma unroll
            for (int e = 0; e < 32; e++)
                g = fmaf(w1p[s * 264 + a * 33 + e], tpp[s * 36 + e], g);
            out[NB + (size_t)b * 8 + a] = g;
        }
        if (tid < 32) {
            const int s2 = tid, b2 = base + s2;
            float v = bv2[0];
            #pragma unroll
            for (int e = 0; e < 32; e++) v = fmaf(v1p[s2 * 36 + e], Wv2[e], v);
            float qt = v;
            #pragma unroll
            for (int e = 0; e < 32; e++)
                qt = fmaf(hidp[s2 * 36 + e], wfp[s2 * 36 + e], qt);
            out[b2] = qt;
        }
    }
#undef LDA3
#undef MMA3
#undef LDB2
#undef MMB2
#undef LDP4
#undef MMP4
}

extern "C" void kernel_launch(void* const* d_in, const int* in_sizes, int n_in,
                              void* d_out, int out_size, void* d_ws, size_t ws_size,
                              hipStream_t stream) {
    const float* agent_qs = (const float*)d_in[0];
    // d_in[1] = hist (unused by reference)
    const float* states   = (const float*)d_in[2];
    // d_in[3] = obs (unused by reference)
    const float* W_tok = (const float*)d_in[4];
    const float* b_tok = (const float*)d_in[5];
    const float* W_yfc = (const float*)d_in[6];
    const float* b_yfc = (const float*)d_in[7];
    const float* W1a   = (const float*)d_in[8];
    const float* b1a   = (const float*)d_in[9];
    const float* W1b   = (const float*)d_in[10];
    const float* b1b   = (const float*)d_in[11];
    const float* Wfa   = (const float*)d_in[12];
    const float* bfa   = (const float*)d_in[13];
    const float* Wfb   = (const float*)d_in[14];
    const float* bfb   = (const float*)d_in[15];
    const float* Wb1   = (const float*)d_in[16];
    const float* bb1   = (const float*)d_in[17];
    const float* Wv1   = (const float*)d_in[18];
    const float* bv1   = (const float*)d_in[19];
    const float* Wv2   = (const float*)d_in[20];
    const float* bv2   = (const float*)d_in[21];
    float* out = (float*)d_out;
    ush* ws = (ush*)d_ws;   // needs 1,622,016 B

    xmix_prep<<<102, 256, 0, stream>>>(W_tok, W_yfc, W1a, W1b, Wfa, Wfb, Wb1, Wv1, ws);
    xmix_mfma<<<NBLOCKS, THREADS, 0, stream>>>(
        agent_qs, states, ws, b_tok, b_yfc, b1a, b1b, bfa, bfb,
        bb1, bv1, Wv2, bv2, out);
}

// Round 7
// 264.728 us; speedup vs baseline: 1.4622x; 1.4622x over previous
//
#include <hip/hip_runtime.h>
#include <math.h>

// XMIX mixing network — split-bf16 MFMA (R1 structure) + fragment-major weights.
// R6/R7: weight fragments stored so each wave's 16B/lane load is lane-consecutive
// (coalesced 1KB burst) instead of 1KB-strided (16 scattered lines / instr).
// Main kernel logic identical to the verified R1 kernel (absmax 4.9e-4).
// R7 fix: removed undeclared dummy-helper call (compile error); dead branch.

#define NB 32768
#define TB 64
#define THREADS 512
#define NBLOCKS (NB / TB)   // 512

typedef short sh8 __attribute__((ext_vector_type(8)));  // 8 bf16 (4 VGPR)
typedef float f4 __attribute__((ext_vector_type(4)));   // MFMA C/D
typedef unsigned short ush;

// ---- workspace layout (ushort units), fragment-major:
//   addr = ((tile*NKC + kc)*64 + lane)*8,  tile = col/16, kc = k/32.
#define OFF_WCAT_H 0         // 40 tiles x 16 kc  (W1a|Wfa|Wb1|Wv1|pad)
#define OFF_WCAT_L 327680
#define OFF_W1B_H  655360    // 16 tiles x 8 kc
#define OFF_W1B_L  720896
#define OFF_WFB_H  786432    // 2 tiles x 8 kc
#define OFF_WFB_L  794624
#define OFF_TOK_H  802816    // 2 tiles x 2 kc
#define OFF_TOK_L  804864
#define OFF_YFC_H  806912    // 4 tiles x 1 kc
#define OFF_YFC_L  808960
// total shorts = 811008 (1.62 MB of d_ws)

__device__ __forceinline__ ush f2bf(float x) {
    unsigned u = __float_as_uint(x);
    u += 0x7fffu + ((u >> 16) & 1u);        // RNE
    return (ush)(u >> 16);
}
__device__ __forceinline__ float bf2f(ush h) {
    return __uint_as_float(((unsigned)h) << 16);
}
__device__ __forceinline__ void splitbf(float x, ush& h, ush& l) {
    h = f2bf(x);
    l = f2bf(x - bf2f(h));
}
__device__ __forceinline__ f4 mfma(sh8 a, sh8 b, f4 c) {
    return __builtin_amdgcn_mfma_f32_16x16x32_bf16(a, b, c, 0, 0, 0);
}

// LDS swizzles (write and read use the same bijection).
__device__ __forceinline__ unsigned swY(unsigned a) {   // 1024B-stride rows
    return a ^ (((((a >> 10) & 7) ^ ((a >> 7) & 7)) << 4));
}
__device__ __forceinline__ unsigned swH(unsigned a) {   // 512B-stride rows
    return a ^ (((a >> 9) & 7) << 4);
}
__device__ __forceinline__ unsigned swS(unsigned a) {   // 64B-stride scratch
    return a ^ (((a >> 7) & 3) << 4);
}

// ---------------- prep: stage tile in LDS, emit hi/lo fragments ----------------
// src points at the first source row of this K-tile (nk rows x snc cols, take
// scol0..scol0+ncol). Fragments land at ((tg0+tl)*nkcg + kcg0+kl)*64*8.
__device__ void tileFrag(const float* src, int snc, int scol0, int ncol, int nk,
                         ush* dH, ush* dL, int nkcg, int tg0, int kcg0,
                         float (*T)[68])
{
    const int tid = threadIdx.x;
    const int nc4 = ncol >> 2;
    const int s_r = (nc4 == 16) ? 4 : 3;
    for (int i = tid; i < nk * nc4; i += 256) {
        const int r = i >> s_r, c4 = i & (nc4 - 1);
        const float4 v = *(const float4*)(src + (size_t)r * snc + scol0 + c4 * 4);
        T[r][c4 * 4 + 0] = v.x; T[r][c4 * 4 + 1] = v.y;
        T[r][c4 * 4 + 2] = v.z; T[r][c4 * 4 + 3] = v.w;
    }
    __syncthreads();
    const int nkc = nk >> 5;                 // kc groups in this tile
    const int nfrag = (ncol >> 4) * nkc;
    const int l = tid & 63, l16 = l & 15, lq = l >> 4;
    for (int f = tid >> 6; f < nfrag; f += 4) {
        const int tl = f / nkc, kl = f % nkc;
        ush hv[8], lv[8];
        #pragma unroll
        for (int j = 0; j < 8; j++) {
            const float x = T[kl * 32 + lq * 8 + j][tl * 16 + l16];
            ush h, lo; splitbf(x, h, lo);
            hv[j] = h; lv[j] = lo;
        }
        const size_t a = (size_t)(((tg0 + tl) * nkcg + (kcg0 + kl)) * 64 + l) * 8;
        uint4 H, L;
        H.x = (unsigned)hv[0] | ((unsigned)hv[1] << 16);
        H.y = (unsigned)hv[2] | ((unsigned)hv[3] << 16);
        H.z = (unsigned)hv[4] | ((unsigned)hv[5] << 16);
        H.w = (unsigned)hv[6] | ((unsigned)hv[7] << 16);
        L.x = (unsigned)lv[0] | ((unsigned)lv[1] << 16);
        L.y = (unsigned)lv[2] | ((unsigned)lv[3] << 16);
        L.z = (unsigned)lv[4] | ((unsigned)lv[5] << 16);
        L.w = (unsigned)lv[6] | ((unsigned)lv[7] << 16);
        *(uint4*)(dH + a) = H;
        *(uint4*)(dL + a) = L;
    }
    __syncthreads();
}

__global__ __launch_bounds__(256) void xmix_prep(
    const float* __restrict__ W_tok, const float* __restrict__ W_yfc,
    const float* __restrict__ W1a, const float* __restrict__ W1b,
    const float* __restrict__ Wfa, const float* __restrict__ Wfb,
    const float* __restrict__ Wb1, const float* __restrict__ Wv1,
    ush* __restrict__ ws)
{
    __shared__ float T[64][68];
    const int b = blockIdx.x;
    if (b < 80) {                    // Wcat: K=512 (nkcg=16), 40 tiles
        const int kt = b / 10, ct = b % 10;
        const int k0 = kt * 64, kcg0 = kt * 2;
        if (ct < 4) {
            tileFrag(W1a + (size_t)k0 * 256, 256, ct * 64, 64, 64,
                     ws + OFF_WCAT_H, ws + OFF_WCAT_L, 16, ct * 4, kcg0, T);
        } else if (ct < 8) {
            tileFrag(Wfa + (size_t)k0 * 256, 256, (ct - 4) * 64, 64, 64,
                     ws + OFF_WCAT_H, ws + OFF_WCAT_L, 16, 16 + (ct - 4) * 4, kcg0, T);
        } else if (ct == 8) {
            tileFrag(Wb1 + (size_t)k0 * 32, 32, 0, 32, 64,
                     ws + OFF_WCAT_H, ws + OFF_WCAT_L, 16, 32, kcg0, T);
            tileFrag(Wv1 + (size_t)k0 * 32, 32, 0, 32, 64,
                     ws + OFF_WCAT_H, ws + OFF_WCAT_L, 16, 34, kcg0, T);
        } else {                     // ct == 9: zero-fill pad tiles 36..39
            const int l = threadIdx.x & 63;
            const uint4 z = {0, 0, 0, 0};
            for (int f = threadIdx.x >> 6; f < 8; f += 4) {
                const int tl = f >> 1, kl = f & 1;
                const size_t a = (size_t)(((36 + tl) * 16 + (kcg0 + kl)) * 64 + l) * 8;
                *(uint4*)(ws + OFF_WCAT_H + a) = z;
                *(uint4*)(ws + OFF_WCAT_L + a) = z;
            }
        }
    } else if (b < 96) {             // W1b: K=256 (nkcg=8), 16 tiles
        const int i = b - 80, kt = i >> 2, ct = i & 3;
        tileFrag(W1b + (size_t)(kt * 64) * 256, 256, ct * 64, 64, 64,
                 ws + OFF_W1B_H, ws + OFF_W1B_L, 8, ct * 4, kt * 2, T);
    } else if (b < 100) {            // Wfb: K=256 (nkcg=8), 2 tiles
        const int kt = b - 96;
        tileFrag(Wfb + (size_t)(kt * 64) * 32, 32, 0, 32, 64,
                 ws + OFF_WFB_H, ws + OFF_WFB_L, 8, 0, kt * 2, T);
    } else if (b == 100) {           // W_tok: K=64 (nkcg=2), 2 tiles
        tileFrag(W_tok, 32, 0, 32, 64, ws + OFF_TOK_H, ws + OFF_TOK_L, 2, 0, 0, T);
    } else {                         // W_yfc: K=32 (nkcg=1), 4 tiles
        tileFrag(W_yfc, 64, 0, 64, 32, ws + OFF_YFC_H, ws + OFF_YFC_L, 1, 0, 0, T);
    }
}

// ---------------- main fused kernel (R1 structure) ----------------
__global__ __launch_bounds__(THREADS, 2) void xmix_mfma(
    const float* __restrict__ agent_qs,
    const float* __restrict__ states,
    const ush* __restrict__ ws,
    const float* __restrict__ b_tok, const float* __restrict__ b_yfc,
    const float* __restrict__ b1a,  const float* __restrict__ b1b,
    const float* __restrict__ bfa,  const float* __restrict__ bfb,
    const float* __restrict__ bb1,  const float* __restrict__ bv1,
    const float* __restrict__ Wv2,  const float* __restrict__ bv2,
    float* __restrict__ out)
{
    // BB phases:
    //  (1) states-split: hi[64][512]bf16 @0 (64KB), lo @65536
    //  (2) y-split: same layout (per-wave in-place overwrite)
    //  (3) H1-hi @0 (32KB), H1-lo @32768, HF-hi @65536, HF-lo @98304
    //  (4) w1 f32 [64][264] (a*33+e) @0 (67584), wf f32 [64][33] @67584 (8448),
    //      hidden [64][33] @76032, tprod @84480 (end 92928)
    __shared__ __align__(16) unsigned char BBs[131072];
    // SM: e-scratch (2KB/wave) -> b1 f32 [64][32] @0, v1 @8192
    __shared__ __align__(16) unsigned char SMs[16384];

    const int tid = threadIdx.x;
    const int wv = tid >> 6;          // wave 0..7
    const int l   = tid & 63;
    const int l16 = l & 15;
    const int lq  = l >> 4;
    const int base = blockIdx.x * TB;
    const f4 fzero = {0.f, 0.f, 0.f, 0.f};

    // ---- P0: load states tile, split to bf16 hi/lo planes in LDS ----
    {
        const float4* gs = (const float4*)(states + (size_t)base * 512);
        #pragma unroll
        for (int i = 0; i < 16; i++) {
            const int idx4 = tid + THREADS * i;
            const float4 v = gs[idx4];
            const int e0 = idx4 * 4;
            const int s = e0 >> 9, c = e0 & 511;
            ush h0, h1, h2, h3, q0, q1, q2, q3;
            splitbf(v.x, h0, q0); splitbf(v.y, h1, q1);
            splitbf(v.z, h2, q2); splitbf(v.w, h3, q3);
            const unsigned sa = swY((unsigned)(s * 1024 + c * 2));
            uint2 uh, ul;
            uh.x = (unsigned)h0 | ((unsigned)h1 << 16);
            uh.y = (unsigned)h2 | ((unsigned)h3 << 16);
            ul.x = (unsigned)q0 | ((unsigned)q1 << 16);
            ul.y = (unsigned)q2 | ((unsigned)q3 << 16);
            *(uint2*)(&BBs[sa])         = uh;
            *(uint2*)(&BBs[65536 + sa]) = ul;
        }
    }
    __syncthreads();

    // ---- P1+P2: e = relu(s@W_tok+b) ; y = relu(e@W_yfc+b) -> Y-split over BB ----
    {
        const ush* tokH = ws + OFF_TOK_H;
        const ush* tokL = ws + OFF_TOK_L;
        const ush* yfcH = ws + OFF_YFC_H;
        const ush* yfcL = ws + OFF_YFC_L;
        unsigned char* scr = &SMs[wv * 2048];   // e-split: hi[16][32] @0, lo @1024

        float btok[2];
        btok[0] = b_tok[l16]; btok[1] = b_tok[16 + l16];
        float byfc[4];
        #pragma unroll
        for (int n = 0; n < 4; n++) byfc[n] = b_yfc[n * 16 + l16];

        sh8 TBh[2][2], TBl[2][2];
        #pragma unroll
        for (int n = 0; n < 2; n++)
            #pragma unroll
            for (int kc = 0; kc < 2; kc++) {
                const int fo = ((n * 2 + kc) * 64 + l) * 8;   // fragment-major
                TBh[n][kc] = *(const sh8*)(tokH + fo);
                TBl[n][kc] = *(const sh8*)(tokL + fo);
            }
        sh8 YBh[4], YBl[4];
        #pragma unroll
        for (int n = 0; n < 4; n++) {
            const int fo = (n * 64 + l) * 8;
            YBh[n] = *(const sh8*)(yfcH + fo);
            YBl[n] = *(const sh8*)(yfcL + fo);
        }

        #pragma unroll
        for (int i = 0; i < 4; i++) {
            const int rt = wv * 4 + i;                 // e-row tile
            const int r = rt * 16 + l16;               // agent-row 0..511
            const int s = r >> 3, a = r & 7;
            f4 eacc[2] = {fzero, fzero};
            #pragma unroll
            for (int kc = 0; kc < 2; kc++) {
                const unsigned ad = (unsigned)(s * 1024 + (a * 64 + kc * 32 + lq * 8) * 2);
                const unsigned sa = swY(ad);
                const sh8 Ah = *(const sh8*)(&BBs[sa]);
                const sh8 Al = *(const sh8*)(&BBs[65536 + sa]);
                #pragma unroll
                for (int n = 0; n < 2; n++) {
                    eacc[n] = mfma(Ah, TBh[n][kc], eacc[n]);
                    eacc[n] = mfma(Ah, TBl[n][kc], eacc[n]);
                    eacc[n] = mfma(Al, TBh[n][kc], eacc[n]);
                }
            }
            // e -> per-wave scratch (split, swizzled)
            #pragma unroll
            for (int n = 0; n < 2; n++)
                #pragma unroll
                for (int j = 0; j < 4; j++) {
                    const float e = fmaxf(eacc[n][j] + btok[n], 0.f);
                    const unsigned sa = swS((unsigned)((lq * 4 + j) * 64 + (n * 16 + l16) * 2));
                    ush hh, ll; splitbf(e, hh, ll);
                    *(ush*)(scr + sa)        = hh;
                    *(ush*)(scr + 1024 + sa) = ll;
                }
            // P2: y-tile = e-tile @ W_yfc
            f4 yacc[4] = {fzero, fzero, fzero, fzero};
            {
                const unsigned sa = swS((unsigned)(l16 * 64 + lq * 16));
                const sh8 Ah = *(const sh8*)(scr + sa);
                const sh8 Al = *(const sh8*)(scr + 1024 + sa);
                #pragma unroll
                for (int n = 0; n < 4; n++) {
                    yacc[n] = mfma(Ah, YBh[n], yacc[n]);
                    yacc[n] = mfma(Ah, YBl[n], yacc[n]);
                    yacc[n] = mfma(Al, YBh[n], yacc[n]);
                }
            }
            // y -> Y-split (overwrite this wave's rows)
            #pragma unroll
            for (int n = 0; n < 4; n++)
                #pragma unroll
                for (int j = 0; j < 4; j++) {
                    const float y = fmaxf(yacc[n][j] + byfc[n], 0.f);
                    const int rr = rt * 16 + lq * 4 + j;
                    const int ss = rr >> 3, aa = rr & 7, ff = n * 16 + l16;
                    const unsigned sa = swY((unsigned)(ss * 1024 + (aa * 64 + ff) * 2));
                    ush hh, ll; splitbf(y, hh, ll);
                    *(ush*)(&BBs[sa])         = hh;
                    *(ush*)(&BBs[65536 + sa]) = ll;
                }
        }
    }
    __syncthreads();

    // ---- P3: Y[64,512] @ Wcat[512,640] -> H1|HF|b1|v1 ----
    f4 acc3[4][5];
    #pragma unroll
    for (int m = 0; m < 4; m++)
        #pragma unroll
        for (int t = 0; t < 5; t++) acc3[m][t] = fzero;
    {
        const ush* wcH = ws + OFF_WCAT_H;
        const ush* wcL = ws + OFF_WCAT_L;
        int cb[5];
        #pragma unroll
        for (int t = 0; t < 5; t++) cb[t] = (wv * 5 + t) * 8192;   // tile*16kc*64l*8
        int rowb[4];
        #pragma unroll
        for (int m = 0; m < 4; m++) rowb[m] = (m * 16 + l16) * 1024;

        sh8 BhA[5], BlA[5], BhB[5], BlB[5];

#define LOADB(BH, BL, KC) { const int fo_ = (KC) * 512 + l * 8; \
        _Pragma("unroll") \
        for (int t = 0; t < 5; t++) { \
            BH[t] = *(const sh8*)(wcH + cb[t] + fo_); \
            BL[t] = *(const sh8*)(wcL + cb[t] + fo_); \
        } }

#define DOMFMA(BH, BL, KC) { \
        const int ko_ = (KC) * 32 + lq * 8; \
        sh8 Ah_[4], Al_[4]; \
        _Pragma("unroll") \
        for (int m = 0; m < 4; m++) { \
            const unsigned sa_ = swY((unsigned)(rowb[m] + ko_ * 2)); \
            Ah_[m] = *(const sh8*)(&BBs[sa_]); \
            Al_[m] = *(const sh8*)(&BBs[65536 + sa_]); \
        } \
        _Pragma("unroll") \
        for (int m = 0; m < 4; m++) \
            _Pragma("unroll") \
            for (int t = 0; t < 5; t++) acc3[m][t] = mfma(Ah_[m], BH[t], acc3[m][t]); \
        _Pragma("unroll") \
        for (int m = 0; m < 4; m++) \
            _Pragma("unroll") \
            for (int t = 0; t < 5; t++) acc3[m][t] = mfma(Ah_[m], BL[t], acc3[m][t]); \
        _Pragma("unroll") \
        for (int m = 0; m < 4; m++) \
            _Pragma("unroll") \
            for (int t = 0; t < 5; t++) acc3[m][t] = mfma(Al_[m], BH[t], acc3[m][t]); \
        }

        LOADB(BhA, BlA, 0);
        #pragma unroll 1
        for (int kc2 = 0; kc2 < 8; kc2++) {
            LOADB(BhB, BlB, kc2 * 2 + 1);
            DOMFMA(BhA, BlA, kc2 * 2);
            LOADB(BhA, BlA, kc2 * 2 + 2);   // kc=16 overshoot: in-bounds garbage, unused
            DOMFMA(BhB, BlB, kc2 * 2 + 1);
        }
#undef LOADB
#undef DOMFMA
    }
    __syncthreads();   // all waves done reading Y

    // ---- P3 epilogue: acc3 -> H1-split / HF-split / b1 / v1 ----
    {
        #pragma unroll
        for (int t = 0; t < 5; t++) {
            const int gt = wv * 5 + t;
            const int cg = gt * 16 + l16;
            if (gt < 16) {                       // H1 = relu(y@W1a + b1a)
                const float bias = b1a[cg];
                #pragma unroll
                for (int m = 0; m < 4; m++)
                    #pragma unroll
                    for (int j = 0; j < 4; j++) {
                        const int row = m * 16 + lq * 4 + j;
                        const float h = fmaxf(acc3[m][t][j] + bias, 0.f);
                        ush hh, ll; splitbf(h, hh, ll);
                        const unsigned sa = swH((unsigned)(row * 512 + cg * 2));
                        *(ush*)(&BBs[sa])         = hh;
                        *(ush*)(&BBs[32768 + sa]) = ll;
                    }
            } else if (gt < 32) {                // HF = relu(y@Wfa + bfa)
                const int c = cg - 256;
                const float bias = bfa[c];
                #pragma unroll
                for (int m = 0; m < 4; m++)
                    #pragma unroll
                    for (int j = 0; j < 4; j++) {
                        const int row = m * 16 + lq * 4 + j;
                        const float h = fmaxf(acc3[m][t][j] + bias, 0.f);
                        ush hh, ll; splitbf(h, hh, ll);
                        const unsigned sa = swH((unsigned)(row * 512 + c * 2));
                        *(ush*)(&BBs[65536 + sa]) = hh;
                        *(ush*)(&BBs[98304 + sa]) = ll;
                    }
            } else if (gt < 34) {                // b1 = y@Wb1 + bb1 (no relu)
                const int c = cg - 512;
                const float bias = bb1[c];
                #pragma unroll
                for (int m = 0; m < 4; m++)
                    #pragma unroll
                    for (int j = 0; j < 4; j++) {
                        const int row = m * 16 + lq * 4 + j;
                        *(float*)(&SMs[(row * 32 + c) * 4]) = acc3[m][t][j] + bias;
                    }
            } else if (gt < 36) {                // v1 = relu(y@Wv1 + bv1)
                const int c = cg - 544;
                const float bias = bv1[c];
                #pragma unroll
                for (int m = 0; m < 4; m++)
                    #pragma unroll
                    for (int j = 0; j < 4; j++) {
                        const int row = m * 16 + lq * 4 + j;
                        *(float*)(&SMs[8192 + (row * 32 + c) * 4]) =
                            fmaxf(acc3[m][t][j] + bias, 0.f);
                    }
            } // gt>=36: pad, discard
        }
    }
    __syncthreads();

    // ---- P4: w1 = |H1@W1b + b1b| ; wf = |HF@Wfb + bfb| ----
    f4 acc4[4][2];
    #pragma unroll
    for (int m = 0; m < 4; m++) { acc4[m][0] = fzero; acc4[m][1] = fzero; }
    f4 accw = fzero;
    {
        const ush* w1H = ws + OFF_W1B_H;
        const ush* w1L = ws + OFF_W1B_L;
        const ush* wfH = ws + OFF_WFB_H;
        const ush* wfL = ws + OFF_WFB_L;
        const int mw = wv & 3, nw = wv >> 2;     // wf tile (M,N)
        const int cb0 = (wv * 2 + 0) * 4096;     // W1b tile stride = 8kc*64l*8
        const int cb1 = (wv * 2 + 1) * 4096;
        const int cbw = nw * 4096;
        #pragma unroll 2
        for (int kc = 0; kc < 8; kc++) {
            const int fo = kc * 512 + l * 8;
            const int ko = kc * 32 + lq * 8;
            const sh8 B0h = *(const sh8*)(w1H + cb0 + fo);
            const sh8 B0l = *(const sh8*)(w1L + cb0 + fo);
            const sh8 B1h = *(const sh8*)(w1H + cb1 + fo);
            const sh8 B1l = *(const sh8*)(w1L + cb1 + fo);
            const sh8 Wh  = *(const sh8*)(wfH + cbw + fo);
            const sh8 Wl  = *(const sh8*)(wfL + cbw + fo);
            sh8 Ah[4], Al[4];
            #pragma unroll
            for (int m = 0; m < 4; m++) {
                const unsigned sa = swH((unsigned)((m * 16 + l16) * 512 + ko * 2));
                Ah[m] = *(const sh8*)(&BBs[sa]);
                Al[m] = *(const sh8*)(&BBs[32768 + sa]);
            }
            const unsigned saw = swH((unsigned)((mw * 16 + l16) * 512 + ko * 2));
            const sh8 Awh = *(const sh8*)(&BBs[65536 + saw]);
            const sh8 Awl = *(const sh8*)(&BBs[98304 + saw]);
            #pragma unroll
            for (int m = 0; m < 4; m++) {
                acc4[m][0] = mfma(Ah[m], B0h, acc4[m][0]);
                acc4[m][1] = mfma(Ah[m], B1h, acc4[m][1]);
            }
            accw = mfma(Awh, Wh, accw);
            #pragma unroll
            for (int m = 0; m < 4; m++) {
                acc4[m][0] = mfma(Ah[m], B0l, acc4[m][0]);
                acc4[m][1] = mfma(Ah[m], B1l, acc4[m][1]);
            }
            accw = mfma(Awh, Wl, accw);
            #pragma unroll
            for (int m = 0; m < 4; m++) {
                acc4[m][0] = mfma(Al[m], B0h, acc4[m][0]);
                acc4[m][1] = mfma(Al[m], B1h, acc4[m][1]);
            }
            accw = mfma(Awl, Wh, accw);
        }
    }
    __syncthreads();   // H1/HF consumed

    // w1/wf -> f32 LDS (de-conflicted: w1 [64][264] a*33+e, wf [64][33])
    {
        #pragma unroll
        for (int t = 0; t < 2; t++) {
            const int col = (wv * 2 + t) * 16 + l16;
            const int a = col >> 5, e = col & 31;
            const float bias = b1b[col];
            #pragma unroll
            for (int m = 0; m < 4; m++)
                #pragma unroll
                for (int j = 0; j < 4; j++) {
                    const int row = m * 16 + lq * 4 + j;
                    *(float*)(&BBs[(row * 264 + a * 33 + e) * 4]) =
                        fabsf(acc4[m][t][j] + bias);
                }
        }
        {
            const int mw = wv & 3, nw = wv >> 2;
            const int col = nw * 16 + l16;
            const float bias = bfb[col];
            #pragma unroll
            for (int j = 0; j < 4; j++) {
                const int row = mw * 16 + lq * 4 + j;
                *(float*)(&BBs[67584 + (row * 33 + col) * 4]) =
                    fabsf(accw[j] + bias);
            }
        }
    }
    __syncthreads();

    // ---- P5: epilogue (elu, delu, q_tot, grad) ----
    {
        const int s = tid >> 3, li = tid & 7;
        const int b = base + s;
        float q[8];
        #pragma unroll
        for (int a = 0; a < 8; a++) q[a] = agent_qs[(size_t)b * 8 + a];
        const float* w1p = (const float*)(&BBs[0]);        // [64][264], a*33+e
        const float* wfp = (const float*)(&BBs[67584]);    // [64][33]
        const float* b1p = (const float*)(&SMs[0]);        // [64][32]
        float* hidp = (float*)(&BBs[76032]);               // [64][33]
        float* tpp  = (float*)(&BBs[84480]);               // [64][33]
        #pragma unroll
        for (int ii = 0; ii < 4; ii++) {
            const int e = li + 8 * ii;
            float z = b1p[s * 32 + e];
            #pragma unroll
            for (int a = 0; a < 8; a++) z = fmaf(q[a], w1p[s * 264 + a * 33 + e], z);
            const float h = (z > 0.f) ? z : (expf(z) - 1.f);   // elu
            const float d = (h < 0.f) ? expf(h) : 1.f;          // delu of elu OUTPUT (ref!)
            hidp[s * 33 + e] = h;
            tpp[s * 33 + e] = d * wfp[s * 33 + e];
        }
    }
    __syncthreads();
    {
        const float* w1p = (const float*)(&BBs[0]);
        const float* wfp = (const float*)(&BBs[67584]);
        const float* v1p = (const float*)(&SMs[8192]);
        const float* hidp = (const float*)(&BBs[76032]);
        const float* tpp  = (const float*)(&BBs[84480]);
        {
            const int s = tid >> 3, a = tid & 7;
            const int b = base + s;
            float g = 0.f;
            #pragma unroll
            for (int e = 0; e < 32; e++)
                g = fmaf(w1p[s * 264 + a * 33 + e], tpp[s * 33 + e], g);
            out[NB + (size_t)b * 8 + a] = g;
        }
        if (tid < 64) {
            const int s2 = tid, b2 = base + s2;
            float v = bv2[0];
            #pragma unroll
            for (int e = 0; e < 32; e++) v = fmaf(v1p[s2 * 32 + e], Wv2[e], v);
            float qt = v;
            #pragma unroll
            for (int e = 0; e < 32; e++)
                qt = fmaf(hidp[s2 * 33 + e], wfp[s2 * 33 + e], qt);
            out[b2] = qt;
        }
    }
}

extern "C" void kernel_launch(void* const* d_in, const int* in_sizes, int n_in,
                              void* d_out, int out_size, void* d_ws, size_t ws_size,
                              hipStream_t stream) {
    const float* agent_qs = (const float*)d_in[0];
    // d_in[1] = hist (unused by reference)
    const float* states   = (const float*)d_in[2];
    // d_in[3] = obs (unused by reference)
    const float* W_tok = (const float*)d_in[4];
    const float* b_tok = (const float*)d_in[5];
    const float* W_yfc = (const float*)d_in[6];
    const float* b_yfc = (const float*)d_in[7];
    const float* W1a   = (const float*)d_in[8];
    const float* b1a   = (const float*)d_in[9];
    const float* W1b   = (const float*)d_in[10];
    const float* b1b   = (const float*)d_in[11];
    const float* Wfa   = (const float*)d_in[12];
    const float* bfa   = (const float*)d_in[13];
    const float* Wfb   = (const float*)d_in[14];
    const float* bfb   = (const float*)d_in[15];
    const float* Wb1   = (const float*)d_in[16];
    const float* bb1   = (const float*)d_in[17];
    const float* Wv1   = (const float*)d_in[18];
    const float* bv1   = (const float*)d_in[19];
    const float* Wv2   = (const float*)d_in[20];
    const float* bv2   = (const float*)d_in[21];
    float* out = (float*)d_out;
    ush* ws = (ush*)d_ws;   // needs 1,622,016 B

    xmix_prep<<<102, 256, 0, stream>>>(W_tok, W_yfc, W1a, W1b, Wfa, Wfb, Wb1, Wv1, ws);
    xmix_mfma<<<NBLOCKS, THREADS, 0, stream>>>(
        agent_qs, states, ws, b_tok, b_yfc, b1a, b1b, bfa, bfb,
        bb1, bv1, Wv2, bv2, out);
}

// Round 8
// 250.243 us; speedup vs baseline: 1.5468x; 1.0579x over previous
//
#include <hip/hip_runtime.h>
#include <math.h>

// XMIX mixing network — split-bf16 MFMA, fragment-major weights (R7, 107.6us)
// R8: (1) P0 removed — P1 loads states A-frags direct from global w/ register
// split (R3-verified pattern); (2) P3 rebalanced: 36 real tiles as 4x5 + 4x4
// waves (pad tiles no longer computed); (3) prep widened to 110 1-tile blocks.

#define NB 32768
#define TB 64
#define THREADS 512
#define NBLOCKS (NB / TB)   // 512

typedef short sh8 __attribute__((ext_vector_type(8)));  // 8 bf16 (4 VGPR)
typedef float f4 __attribute__((ext_vector_type(4)));   // MFMA C/D
typedef unsigned short ush;

// ---- workspace layout (ushort units), fragment-major:
//   addr = ((tile*NKC + kc)*64 + lane)*8,  tile = col/16, kc = k/32.
#define OFF_WCAT_H 0         // 40 tiles x 16 kc  (W1a|Wfa|Wb1|Wv1|pad)
#define OFF_WCAT_L 327680
#define OFF_W1B_H  655360    // 16 tiles x 8 kc
#define OFF_W1B_L  720896
#define OFF_WFB_H  786432    // 2 tiles x 8 kc
#define OFF_WFB_L  794624
#define OFF_TOK_H  802816    // 2 tiles x 2 kc
#define OFF_TOK_L  804864
#define OFF_YFC_H  806912    // 4 tiles x 1 kc
#define OFF_YFC_L  808960
// total shorts = 811008 (1.62 MB of d_ws)

__device__ __forceinline__ ush f2bf(float x) {
    unsigned u = __float_as_uint(x);
    u += 0x7fffu + ((u >> 16) & 1u);        // RNE
    return (ush)(u >> 16);
}
__device__ __forceinline__ float bf2f(ush h) {
    return __uint_as_float(((unsigned)h) << 16);
}
__device__ __forceinline__ void splitbf(float x, ush& h, ush& l) {
    h = f2bf(x);
    l = f2bf(x - bf2f(h));
}
__device__ __forceinline__ f4 mfma(sh8 a, sh8 b, f4 c) {
    return __builtin_amdgcn_mfma_f32_16x16x32_bf16(a, b, c, 0, 0, 0);
}
__device__ __forceinline__ void split8(const float4 v0, const float4 v1, sh8& Ah, sh8& Al) {
    ush h, l;
    splitbf(v0.x, h, l); Ah[0] = (short)h; Al[0] = (short)l;
    splitbf(v0.y, h, l); Ah[1] = (short)h; Al[1] = (short)l;
    splitbf(v0.z, h, l); Ah[2] = (short)h; Al[2] = (short)l;
    splitbf(v0.w, h, l); Ah[3] = (short)h; Al[3] = (short)l;
    splitbf(v1.x, h, l); Ah[4] = (short)h; Al[4] = (short)l;
    splitbf(v1.y, h, l); Ah[5] = (short)h; Al[5] = (short)l;
    splitbf(v1.z, h, l); Ah[6] = (short)h; Al[6] = (short)l;
    splitbf(v1.w, h, l); Ah[7] = (short)h; Al[7] = (short)l;
}

// LDS swizzles (write and read use the same bijection).
__device__ __forceinline__ unsigned swY(unsigned a) {   // 1024B-stride rows
    return a ^ (((((a >> 10) & 7) ^ ((a >> 7) & 7)) << 4));
}
__device__ __forceinline__ unsigned swH(unsigned a) {   // 512B-stride rows
    return a ^ (((a >> 9) & 7) << 4);
}
__device__ __forceinline__ unsigned swS(unsigned a) {   // 64B-stride scratch
    return a ^ (((a >> 7) & 3) << 4);
}

// ---------------- prep: stage tile in LDS, emit hi/lo fragments ----------------
__device__ void tileFrag(const float* src, int snc, int scol0, int ncol, int nk,
                         ush* dH, ush* dL, int nkcg, int tg0, int kcg0,
                         float (*T)[68])
{
    const int tid = threadIdx.x;
    const int nc4 = ncol >> 2;
    const int s_r = (nc4 == 16) ? 4 : 3;
    for (int i = tid; i < nk * nc4; i += 256) {
        const int r = i >> s_r, c4 = i & (nc4 - 1);
        const float4 v = *(const float4*)(src + (size_t)r * snc + scol0 + c4 * 4);
        T[r][c4 * 4 + 0] = v.x; T[r][c4 * 4 + 1] = v.y;
        T[r][c4 * 4 + 2] = v.z; T[r][c4 * 4 + 3] = v.w;
    }
    __syncthreads();
    const int nkc = nk >> 5;                 // kc groups in this tile
    const int nfrag = (ncol >> 4) * nkc;
    const int l = tid & 63, l16 = l & 15, lq = l >> 4;
    for (int f = tid >> 6; f < nfrag; f += 4) {
        const int tl = f / nkc, kl = f % nkc;
        ush hv[8], lv[8];
        #pragma unroll
        for (int j = 0; j < 8; j++) {
            const float x = T[kl * 32 + lq * 8 + j][tl * 16 + l16];
            ush h, lo; splitbf(x, h, lo);
            hv[j] = h; lv[j] = lo;
        }
        const size_t a = (size_t)(((tg0 + tl) * nkcg + (kcg0 + kl)) * 64 + l) * 8;
        uint4 H, L;
        H.x = (unsigned)hv[0] | ((unsigned)hv[1] << 16);
        H.y = (unsigned)hv[2] | ((unsigned)hv[3] << 16);
        H.z = (unsigned)hv[4] | ((unsigned)hv[5] << 16);
        H.w = (unsigned)hv[6] | ((unsigned)hv[7] << 16);
        L.x = (unsigned)lv[0] | ((unsigned)lv[1] << 16);
        L.y = (unsigned)lv[2] | ((unsigned)lv[3] << 16);
        L.z = (unsigned)lv[4] | ((unsigned)lv[5] << 16);
        L.w = (unsigned)lv[6] | ((unsigned)lv[7] << 16);
        *(uint4*)(dH + a) = H;
        *(uint4*)(dL + a) = L;
    }
    __syncthreads();
}

__global__ __launch_bounds__(256) void xmix_prep(
    const float* __restrict__ W_tok, const float* __restrict__ W_yfc,
    const float* __restrict__ W1a, const float* __restrict__ W1b,
    const float* __restrict__ Wfa, const float* __restrict__ Wfb,
    const float* __restrict__ Wb1, const float* __restrict__ Wv1,
    ush* __restrict__ ws)
{
    __shared__ float T[64][68];
    const int b = blockIdx.x;
    if (b < 88) {                    // Wcat: K=512 (nkcg=16), kt = b/11, ct = b%11
        const int kt = b / 11, ct = b % 11;
        const int k0 = kt * 64, kcg0 = kt * 2;
        if (ct < 4) {
            tileFrag(W1a + (size_t)k0 * 256, 256, ct * 64, 64, 64,
                     ws + OFF_WCAT_H, ws + OFF_WCAT_L, 16, ct * 4, kcg0, T);
        } else if (ct < 8) {
            tileFrag(Wfa + (size_t)k0 * 256, 256, (ct - 4) * 64, 64, 64,
                     ws + OFF_WCAT_H, ws + OFF_WCAT_L, 16, 16 + (ct - 4) * 4, kcg0, T);
        } else if (ct == 8) {
            tileFrag(Wb1 + (size_t)k0 * 32, 32, 0, 32, 64,
                     ws + OFF_WCAT_H, ws + OFF_WCAT_L, 16, 32, kcg0, T);
        } else if (ct == 9) {
            tileFrag(Wv1 + (size_t)k0 * 32, 32, 0, 32, 64,
                     ws + OFF_WCAT_H, ws + OFF_WCAT_L, 16, 34, kcg0, T);
        } else {                     // zero-fill pad tiles 36..39 (never computed now)
            const int l = threadIdx.x & 63;
            const uint4 z = {0, 0, 0, 0};
            for (int f = threadIdx.x >> 6; f < 8; f += 4) {
                const int tl = f >> 1, kl = f & 1;
                const size_t a = (size_t)(((36 + tl) * 16 + (kcg0 + kl)) * 64 + l) * 8;
                *(uint4*)(ws + OFF_WCAT_H + a) = z;
                *(uint4*)(ws + OFF_WCAT_L + a) = z;
            }
        }
    } else if (b < 104) {            // W1b: K=256 (nkcg=8), 16 tiles
        const int i = b - 88, kt = i >> 2, ct = i & 3;
        tileFrag(W1b + (size_t)(kt * 64) * 256, 256, ct * 64, 64, 64,
                 ws + OFF_W1B_H, ws + OFF_W1B_L, 8, ct * 4, kt * 2, T);
    } else if (b < 108) {            // Wfb: K=256 (nkcg=8), 2 tiles
        const int kt = b - 104;
        tileFrag(Wfb + (size_t)(kt * 64) * 32, 32, 0, 32, 64,
                 ws + OFF_WFB_H, ws + OFF_WFB_L, 8, 0, kt * 2, T);
    } else if (b == 108) {           // W_tok: K=64 (nkcg=2), 2 tiles
        tileFrag(W_tok, 32, 0, 32, 64, ws + OFF_TOK_H, ws + OFF_TOK_L, 2, 0, 0, T);
    } else {                         // W_yfc: K=32 (nkcg=1), 4 tiles
        tileFrag(W_yfc, 64, 0, 64, 32, ws + OFF_YFC_H, ws + OFF_YFC_L, 1, 0, 0, T);
    }
}

// ---------------- main fused kernel ----------------
__global__ __launch_bounds__(THREADS, 2) void xmix_mfma(
    const float* __restrict__ agent_qs,
    const float* __restrict__ states,
    const ush* __restrict__ ws,
    const float* __restrict__ b_tok, const float* __restrict__ b_yfc,
    const float* __restrict__ b1a,  const float* __restrict__ b1b,
    const float* __restrict__ bfa,  const float* __restrict__ bfb,
    const float* __restrict__ bb1,  const float* __restrict__ bv1,
    const float* __restrict__ Wv2,  const float* __restrict__ bv2,
    float* __restrict__ out)
{
    // BB phases:
    //  (1) Y-split bf16: hi [64 rows*8ag][64f] = [512][64] @0 (64KB), lo @65536
    //  (2) H1-hi @0 (32KB), H1-lo @32768, HF-hi @65536, HF-lo @98304
    //  (3) w1 f32 [64][264] (a*33+e) @0 (67584), wf f32 [64][33] @67584,
    //      hidden [64][33] @76032, tprod @84480 (end 92928)
    __shared__ __align__(16) unsigned char BBs[131072];
    // SM: e-scratch (2KB/wave) -> b1 f32 [64][32] @0, v1 @8192
    __shared__ __align__(16) unsigned char SMs[16384];

    const int tid = threadIdx.x;
    const int wv = tid >> 6;          // wave 0..7
    const int l   = tid & 63;
    const int l16 = l & 15;
    const int lq  = l >> 4;
    const int base = blockIdx.x * TB;
    const f4 fzero = {0.f, 0.f, 0.f, 0.f};

    // ---- P1+P2: e = relu(s@W_tok+b) ; y = relu(e@W_yfc+b) -> Y-split in BB ----
    // States A-fragments come straight from global (register split) — no P0.
    {
        const ush* tokH = ws + OFF_TOK_H;
        const ush* tokL = ws + OFF_TOK_L;
        const ush* yfcH = ws + OFF_YFC_H;
        const ush* yfcL = ws + OFF_YFC_L;
        unsigned char* scr = &SMs[wv * 2048];   // e-split: hi[16][32] @0, lo @1024

        float btok[2];
        btok[0] = b_tok[l16]; btok[1] = b_tok[16 + l16];
        float byfc[4];
        #pragma unroll
        for (int n = 0; n < 4; n++) byfc[n] = b_yfc[n * 16 + l16];

        sh8 TBh[2][2], TBl[2][2];
        #pragma unroll
        for (int n = 0; n < 2; n++)
            #pragma unroll
            for (int kc = 0; kc < 2; kc++) {
                const int fo = ((n * 2 + kc) * 64 + l) * 8;   // fragment-major
                TBh[n][kc] = *(const sh8*)(tokH + fo);
                TBl[n][kc] = *(const sh8*)(tokL + fo);
            }
        sh8 YBh[4], YBl[4];
        #pragma unroll
        for (int n = 0; n < 4; n++) {
            const int fo = (n * 64 + l) * 8;
            YBh[n] = *(const sh8*)(yfcH + fo);
            YBl[n] = *(const sh8*)(yfcL + fo);
        }

        #pragma unroll
        for (int i = 0; i < 4; i++) {
            const int rt = wv * 4 + i;                 // e-row tile
            const int r = rt * 16 + l16;               // agent-row 0..511
            const float* srow = states + (size_t)(base + (r >> 3)) * 512 + (r & 7) * 64;
            f4 eacc[2] = {fzero, fzero};
            #pragma unroll
            for (int kc = 0; kc < 2; kc++) {
                const float4 v0 = *(const float4*)(srow + kc * 32 + lq * 8);
                const float4 v1 = *(const float4*)(srow + kc * 32 + lq * 8 + 4);
                sh8 Ah, Al;
                split8(v0, v1, Ah, Al);
                #pragma unroll
                for (int n = 0; n < 2; n++) {
                    eacc[n] = mfma(Ah, TBh[n][kc], eacc[n]);
                    eacc[n] = mfma(Ah, TBl[n][kc], eacc[n]);
                    eacc[n] = mfma(Al, TBh[n][kc], eacc[n]);
                }
            }
            // e -> per-wave scratch (split, swizzled)
            #pragma unroll
            for (int n = 0; n < 2; n++)
                #pragma unroll
                for (int j = 0; j < 4; j++) {
                    const float e = fmaxf(eacc[n][j] + btok[n], 0.f);
                    const unsigned sa = swS((unsigned)((lq * 4 + j) * 64 + (n * 16 + l16) * 2));
                    ush hh, ll; splitbf(e, hh, ll);
                    *(ush*)(scr + sa)        = hh;
                    *(ush*)(scr + 1024 + sa) = ll;
                }
            // P2: y-tile = e-tile @ W_yfc
            f4 yacc[4] = {fzero, fzero, fzero, fzero};
            {
                const unsigned sa = swS((unsigned)(l16 * 64 + lq * 16));
                const sh8 Ah = *(const sh8*)(scr + sa);
                const sh8 Al = *(const sh8*)(scr + 1024 + sa);
                #pragma unroll
                for (int n = 0; n < 4; n++) {
                    yacc[n] = mfma(Ah, YBh[n], yacc[n]);
                    yacc[n] = mfma(Ah, YBl[n], yacc[n]);
                    yacc[n] = mfma(Al, YBh[n], yacc[n]);
                }
            }
            // y -> Y-split planes
            #pragma unroll
            for (int n = 0; n < 4; n++)
                #pragma unroll
                for (int j = 0; j < 4; j++) {
                    const float y = fmaxf(yacc[n][j] + byfc[n], 0.f);
                    const int rr = rt * 16 + lq * 4 + j;
                    const int ss = rr >> 3, aa = rr & 7, ff = n * 16 + l16;
                    const unsigned sa = swY((unsigned)(ss * 1024 + (aa * 64 + ff) * 2));
                    ush hh, ll; splitbf(y, hh, ll);
                    *(ush*)(&BBs[sa])         = hh;
                    *(ush*)(&BBs[65536 + sa]) = ll;
                }
        }
    }

    // ---- P3: Y[64,512] @ Wcat[512,576] -> H1|HF|b1|v1 ----
    // 36 real tiles: waves 0-3 own 5 tiles (0..19), waves 4-7 own 4 (20..35).
    f4 acc3[4][5];
    #pragma unroll
    for (int m = 0; m < 4; m++)
        #pragma unroll
        for (int t = 0; t < 5; t++) acc3[m][t] = fzero;

    const ush* wcH = ws + OFF_WCAT_H;
    const ush* wcL = ws + OFF_WCAT_L;
    const int tb0 = (wv < 4) ? (wv * 5) : (20 + (wv - 4) * 4);
    int cb[5];
    #pragma unroll
    for (int t = 0; t < 5; t++) cb[t] = (tb0 + t) * 8192;   // tile*16kc*64l*8
    int rowb[4];
    #pragma unroll
    for (int m = 0; m < 4; m++) rowb[m] = (m * 16 + l16) * 1024;

    sh8 BhA[5], BlA[5], BhB[5], BlB[5];

#define LOADB(BH, BL, KC, N) { const int fo_ = (KC) * 512 + l * 8; \
    _Pragma("unroll") \
    for (int t = 0; t < N; t++) { \
        BH[t] = *(const sh8*)(wcH + cb[t] + fo_); \
        BL[t] = *(const sh8*)(wcL + cb[t] + fo_); \
    } }

#define DOMFMA(BH, BL, KC, N) { \
    const int ko_ = (KC) * 32 + lq * 8; \
    sh8 Ah_[4], Al_[4]; \
    _Pragma("unroll") \
    for (int m = 0; m < 4; m++) { \
        const unsigned sa_ = swY((unsigned)(rowb[m] + ko_ * 2)); \
        Ah_[m] = *(const sh8*)(&BBs[sa_]); \
        Al_[m] = *(const sh8*)(&BBs[65536 + sa_]); \
    } \
    _Pragma("unroll") \
    for (int m = 0; m < 4; m++) \
        _Pragma("unroll") \
        for (int t = 0; t < N; t++) acc3[m][t] = mfma(Ah_[m], BH[t], acc3[m][t]); \
    _Pragma("unroll") \
    for (int m = 0; m < 4; m++) \
        _Pragma("unroll") \
        for (int t = 0; t < N; t++) acc3[m][t] = mfma(Ah_[m], BL[t], acc3[m][t]); \
    _Pragma("unroll") \
    for (int m = 0; m < 4; m++) \
        _Pragma("unroll") \
        for (int t = 0; t < N; t++) acc3[m][t] = mfma(Al_[m], BH[t], acc3[m][t]); \
    }

    if (wv < 4) { LOADB(BhA, BlA, 0, 5); } else { LOADB(BhA, BlA, 0, 4); }
    __syncthreads();        // Y visible to all waves

    if (wv < 4) {
        #pragma unroll 1
        for (int kc2 = 0; kc2 < 8; kc2++) {
            LOADB(BhB, BlB, kc2 * 2 + 1, 5);
            DOMFMA(BhA, BlA, kc2 * 2, 5);
            LOADB(BhA, BlA, kc2 * 2 + 2, 5);   // kc=16 overshoot: in-bounds, unused
            DOMFMA(BhB, BlB, kc2 * 2 + 1, 5);
        }
    } else {
        #pragma unroll 1
        for (int kc2 = 0; kc2 < 8; kc2++) {
            LOADB(BhB, BlB, kc2 * 2 + 1, 4);
            DOMFMA(BhA, BlA, kc2 * 2, 4);
            LOADB(BhA, BlA, kc2 * 2 + 2, 4);   // overshoot safe
            DOMFMA(BhB, BlB, kc2 * 2 + 1, 4);
        }
    }
#undef LOADB
#undef DOMFMA

    // ---- P4 prefetch kc=0 (in flight across epilogue + barriers) ----
    const ush* w1H = ws + OFF_W1B_H;
    const ush* w1L = ws + OFF_W1B_L;
    const ush* wfH = ws + OFF_WFB_H;
    const ush* wfL = ws + OFF_WFB_L;
    const int mw = wv & 3, nw = wv >> 2;     // wf tile (M,N)
    const int cb0 = (wv * 2 + 0) * 4096;     // W1b tile stride = 8kc*64l*8
    const int cb1 = (wv * 2 + 1) * 4096;
    const int cbw = nw * 4096;

    __syncthreads();   // all waves done reading Y

    // ---- P3 epilogue: acc3 -> H1-split / HF-split / b1 / v1 ----
#define EPIBODY(T_) { \
    const int gt = tb0 + (T_); \
    const int cg = gt * 16 + l16; \
    if (gt < 16) { \
        const float bias = b1a[cg]; \
        _Pragma("unroll") \
        for (int m = 0; m < 4; m++) \
            _Pragma("unroll") \
            for (int j = 0; j < 4; j++) { \
                const int row = m * 16 + lq * 4 + j; \
                const float h = fmaxf(acc3[m][T_][j] + bias, 0.f); \
                ush hh, ll; splitbf(h, hh, ll); \
                const unsigned sa = swH((unsigned)(row * 512 + cg * 2)); \
                *(ush*)(&BBs[sa])         = hh; \
                *(ush*)(&BBs[32768 + sa]) = ll; \
            } \
    } else if (gt < 32) { \
        const int c = cg - 256; \
        const float bias = bfa[c]; \
        _Pragma("unroll") \
        for (int m = 0; m < 4; m++) \
            _Pragma("unroll") \
            for (int j = 0; j < 4; j++) { \
                const int row = m * 16 + lq * 4 + j; \
                const float h = fmaxf(acc3[m][T_][j] + bias, 0.f); \
                ush hh, ll; splitbf(h, hh, ll); \
                const unsigned sa = swH((unsigned)(row * 512 + c * 2)); \
                *(ush*)(&BBs[65536 + sa]) = hh; \
                *(ush*)(&BBs[98304 + sa]) = ll; \
            } \
    } else if (gt < 34) { \
        const int c = cg - 512; \
        const float bias = bb1[c]; \
        _Pragma("unroll") \
        for (int m = 0; m < 4; m++) \
            _Pragma("unroll") \
            for (int j = 0; j < 4; j++) { \
                const int row = m * 16 + lq * 4 + j; \
                *(float*)(&SMs[(row * 32 + c) * 4]) = acc3[m][T_][j] + bias; \
            } \
    } else if (gt < 36) { \
        const int c = cg - 544; \
        const float bias = bv1[c]; \
        _Pragma("unroll") \
        for (int m = 0; m < 4; m++) \
            _Pragma("unroll") \
            for (int j = 0; j < 4; j++) { \
                const int row = m * 16 + lq * 4 + j; \
                *(float*)(&SMs[8192 + (row * 32 + c) * 4]) = \
                    fmaxf(acc3[m][T_][j] + bias, 0.f); \
            } \
    } }

    if (wv < 4) {
        EPIBODY(0) EPIBODY(1) EPIBODY(2) EPIBODY(3) EPIBODY(4)
    } else {
        EPIBODY(0) EPIBODY(1) EPIBODY(2) EPIBODY(3)
    }
#undef EPIBODY
    __syncthreads();

    // ---- P4: w1 = |H1@W1b + b1b| ; wf = |HF@Wfb + bfb| ----
    f4 acc4[4][2];
    #pragma unroll
    for (int m = 0; m < 4; m++) { acc4[m][0] = fzero; acc4[m][1] = fzero; }
    f4 accw = fzero;
    {
        #pragma unroll 2
        for (int kc = 0; kc < 8; kc++) {
            const int fo = kc * 512 + l * 8;
            const int ko = kc * 32 + lq * 8;
            const sh8 B0h = *(const sh8*)(w1H + cb0 + fo);
            const sh8 B0l = *(const sh8*)(w1L + cb0 + fo);
            const sh8 B1h = *(const sh8*)(w1H + cb1 + fo);
            const sh8 B1l = *(const sh8*)(w1L + cb1 + fo);
            const sh8 Wh  = *(const sh8*)(wfH + cbw + fo);
            const sh8 Wl  = *(const sh8*)(wfL + cbw + fo);
            sh8 Ah[4], Al[4];
            #pragma unroll
            for (int m = 0; m < 4; m++) {
                const unsigned sa = swH((unsigned)((m * 16 + l16) * 512 + ko * 2));
                Ah[m] = *(const sh8*)(&BBs[sa]);
                Al[m] = *(const sh8*)(&BBs[32768 + sa]);
            }
            const unsigned saw = swH((unsigned)((mw * 16 + l16) * 512 + ko * 2));
            const sh8 Awh = *(const sh8*)(&BBs[65536 + saw]);
            const sh8 Awl = *(const sh8*)(&BBs[98304 + saw]);
            #pragma unroll
            for (int m = 0; m < 4; m++) {
                acc4[m][0] = mfma(Ah[m], B0h, acc4[m][0]);
                acc4[m][1] = mfma(Ah[m], B1h, acc4[m][1]);
            }
            accw = mfma(Awh, Wh, accw);
            #pragma unroll
            for (int m = 0; m < 4; m++) {
                acc4[m][0] = mfma(Ah[m], B0l, acc4[m][0]);
                acc4[m][1] = mfma(Ah[m], B1l, acc4[m][1]);
            }
            accw = mfma(Awh, Wl, accw);
            #pragma unroll
            for (int m = 0; m < 4; m++) {
                acc4[m][0] = mfma(Al[m], B0h, acc4[m][0]);
                acc4[m][1] = mfma(Al[m], B1h, acc4[m][1]);
            }
            accw = mfma(Awl, Wh, accw);
        }
    }
    __syncthreads();   // H1/HF consumed

    // w1/wf -> f32 LDS (de-conflicted: w1 [64][264] a*33+e, wf [64][33])
    {
        #pragma unroll
        for (int t = 0; t < 2; t++) {
            const int col = (wv * 2 + t) * 16 + l16;
            const int a = col >> 5, e = col & 31;
            const float bias = b1b[col];
            #pragma unroll
            for (int m = 0; m < 4; m++)
                #pragma unroll
                for (int j = 0; j < 4; j++) {
                    const int row = m * 16 + lq * 4 + j;
                    *(float*)(&BBs[(row * 264 + a * 33 + e) * 4]) =
                        fabsf(acc4[m][t][j] + bias);
                }
        }
        {
            const int col = nw * 16 + l16;
            const float bias = bfb[col];
            #pragma unroll
            for (int j = 0; j < 4; j++) {
                const int row = mw * 16 + lq * 4 + j;
                *(float*)(&BBs[67584 + (row * 33 + col) * 4]) =
                    fabsf(accw[j] + bias);
            }
        }
    }
    __syncthreads();

    // ---- P5: epilogue (elu, delu, q_tot, grad) ----
    {
        const int s = tid >> 3, li = tid & 7;
        const int b = base + s;
        float q[8];
        #pragma unroll
        for (int a = 0; a < 8; a++) q[a] = agent_qs[(size_t)b * 8 + a];
        const float* w1p = (const float*)(&BBs[0]);        // [64][264], a*33+e
        const float* wfp = (const float*)(&BBs[67584]);    // [64][33]
        const float* b1p = (const float*)(&SMs[0]);        // [64][32]
        float* hidp = (float*)(&BBs[76032]);               // [64][33]
        float* tpp  = (float*)(&BBs[84480]);               // [64][33]
        #pragma unroll
        for (int ii = 0; ii < 4; ii++) {
            const int e = li + 8 * ii;
            float z = b1p[s * 32 + e];
            #pragma unroll
            for (int a = 0; a < 8; a++) z = fmaf(q[a], w1p[s * 264 + a * 33 + e], z);
            const float h = (z > 0.f) ? z : (expf(z) - 1.f);   // elu
            const float d = (h < 0.f) ? expf(h) : 1.f;          // delu of elu OUTPUT (ref!)
            hidp[s * 33 + e] = h;
            tpp[s * 33 + e] = d * wfp[s * 33 + e];
        }
    }
    __syncthreads();
    {
        const float* w1p = (const float*)(&BBs[0]);
        const float* wfp = (const float*)(&BBs[67584]);
        const float* v1p = (const float*)(&SMs[8192]);
        const float* hidp = (const float*)(&BBs[76032]);
        const float* tpp  = (const float*)(&BBs[84480]);
        {
            const int s = tid >> 3, a = tid & 7;
            const int b = base + s;
            float g = 0.f;
            #pragma unroll
            for (int e = 0; e < 32; e++)
                g = fmaf(w1p[s * 264 + a * 33 + e], tpp[s * 33 + e], g);
            out[NB + (size_t)b * 8 + a] = g;
        }
        if (tid < 64) {
            const int s2 = tid, b2 = base + s2;
            float v = bv2[0];
            #pragma unroll
            for (int e = 0; e < 32; e++) v = fmaf(v1p[s2 * 32 + e], Wv2[e], v);
            float qt = v;
            #pragma unroll
            for (int e = 0; e < 32; e++)
                qt = fmaf(hidp[s2 * 33 + e], wfp[s2 * 33 + e], qt);
            out[b2] = qt;
        }
    }
}

extern "C" void kernel_launch(void* const* d_in, const int* in_sizes, int n_in,
                              void* d_out, int out_size, void* d_ws, size_t ws_size,
                              hipStream_t stream) {
    const float* agent_qs = (const float*)d_in[0];
    // d_in[1] = hist (unused by reference)
    const float* states   = (const float*)d_in[2];
    // d_in[3] = obs (unused by reference)
    const float* W_tok = (const float*)d_in[4];
    const float* b_tok = (const float*)d_in[5];
    const float* W_yfc = (const float*)d_in[6];
    const float* b_yfc = (const float*)d_in[7];
    const float* W1a   = (const float*)d_in[8];
    const float* b1a   = (const float*)d_in[9];
    const float* W1b   = (const float*)d_in[10];
    const float* b1b   = (const float*)d_in[11];
    const float* Wfa   = (const float*)d_in[12];
    const float* bfa   = (const float*)d_in[13];
    const float* Wfb   = (const float*)d_in[14];
    const float* bfb   = (const float*)d_in[15];
    const float* Wb1   = (const float*)d_in[16];
    const float* bb1   = (const float*)d_in[17];
    const float* Wv1   = (const float*)d_in[18];
    const float* bv1   = (const float*)d_in[19];
    const float* Wv2   = (const float*)d_in[20];
    const float* bv2   = (const float*)d_in[21];
    float* out = (float*)d_out;
    ush* ws = (ush*)d_ws;   // needs 1,622,016 B

    xmix_prep<<<110, 256, 0, stream>>>(W_tok, W_yfc, W1a, W1b, Wfa, Wfb, Wb1, Wv1, ws);
    xmix_mfma<<<NBLOCKS, THREADS, 0, stream>>>(
        agent_qs, states, ws, b_tok, b_yfc, b1a, b1b, bfa, bfb,
        bb1, bv1, Wv2, bv2, out);
}

// Round 9
// 249.008 us; speedup vs baseline: 1.5545x; 1.0050x over previous
//
#include <hip/hip_runtime.h>
#include <math.h>

// XMIX mixing network — split-bf16 MFMA, fragment-major weights.
// R8 main kernel verbatim (95us). R9: prep rewritten as direct-gather fragment
// emitter — 1 thread per (fragment,lane), no LDS/barriers/divides; bit-identical
// ws output. Old tiled prep cost ~70us (gap analysis R0/R1/R3/R7/R8).

#define NB 32768
#define TB 64
#define THREADS 512
#define NBLOCKS (NB / TB)   // 512

typedef short sh8 __attribute__((ext_vector_type(8)));  // 8 bf16 (4 VGPR)
typedef float f4 __attribute__((ext_vector_type(4)));   // MFMA C/D
typedef unsigned short ush;

// ---- workspace layout (ushort units), fragment-major:
//   addr = ((tile*NKC + kc)*64 + lane)*8,  tile = col/16, kc = k/32.
#define OFF_WCAT_H 0         // 40 tiles x 16 kc  (W1a|Wfa|Wb1|Wv1|pad)
#define OFF_WCAT_L 327680
#define OFF_W1B_H  655360    // 16 tiles x 8 kc
#define OFF_W1B_L  720896
#define OFF_WFB_H  786432    // 2 tiles x 8 kc
#define OFF_WFB_L  794624
#define OFF_TOK_H  802816    // 2 tiles x 2 kc
#define OFF_TOK_L  804864
#define OFF_YFC_H  806912    // 4 tiles x 1 kc
#define OFF_YFC_L  808960
// total shorts = 811008 (1.62 MB of d_ws)

__device__ __forceinline__ ush f2bf(float x) {
    unsigned u = __float_as_uint(x);
    u += 0x7fffu + ((u >> 16) & 1u);        // RNE
    return (ush)(u >> 16);
}
__device__ __forceinline__ float bf2f(ush h) {
    return __uint_as_float(((unsigned)h) << 16);
}
__device__ __forceinline__ void splitbf(float x, ush& h, ush& l) {
    h = f2bf(x);
    l = f2bf(x - bf2f(h));
}
__device__ __forceinline__ f4 mfma(sh8 a, sh8 b, f4 c) {
    return __builtin_amdgcn_mfma_f32_16x16x32_bf16(a, b, c, 0, 0, 0);
}
__device__ __forceinline__ void split8(const float4 v0, const float4 v1, sh8& Ah, sh8& Al) {
    ush h, l;
    splitbf(v0.x, h, l); Ah[0] = (short)h; Al[0] = (short)l;
    splitbf(v0.y, h, l); Ah[1] = (short)h; Al[1] = (short)l;
    splitbf(v0.z, h, l); Ah[2] = (short)h; Al[2] = (short)l;
    splitbf(v0.w, h, l); Ah[3] = (short)h; Al[3] = (short)l;
    splitbf(v1.x, h, l); Ah[4] = (short)h; Al[4] = (short)l;
    splitbf(v1.y, h, l); Ah[5] = (short)h; Al[5] = (short)l;
    splitbf(v1.z, h, l); Ah[6] = (short)h; Al[6] = (short)l;
    splitbf(v1.w, h, l); Ah[7] = (short)h; Al[7] = (short)l;
}

// LDS swizzles (write and read use the same bijection).
__device__ __forceinline__ unsigned swY(unsigned a) {   // 1024B-stride rows
    return a ^ (((((a >> 10) & 7) ^ ((a >> 7) & 7)) << 4));
}
__device__ __forceinline__ unsigned swH(unsigned a) {   // 512B-stride rows
    return a ^ (((a >> 9) & 7) << 4);
}
__device__ __forceinline__ unsigned swS(unsigned a) {   // 64B-stride scratch
    return a ^ (((a >> 7) & 3) << 4);
}

// ---------------- prep: direct-gather fragment emitter ----------------
// One thread per (fragment, lane). frag value j (j=0..7):
//   W[k0+j][col], k0 = kc*32 + lq*8, col = tile*16 + l16 (within matrix region).
// Writes: lane-consecutive uint4 -> fully coalesced. Reads: 16-lane groups read
// 64 consecutive bytes of a weight row; all weights (2.4 MB) are L2-resident.
__global__ __launch_bounds__(512) void xmix_prep(
    const float* __restrict__ W_tok, const float* __restrict__ W_yfc,
    const float* __restrict__ W1a, const float* __restrict__ W1b,
    const float* __restrict__ Wfa, const float* __restrict__ Wfb,
    const float* __restrict__ Wb1, const float* __restrict__ Wv1,
    ush* __restrict__ ws)
{
    const int gid = blockIdx.x * 512 + threadIdx.x;   // 99*512 = 50688 = 792*64
    const int gf = gid >> 6, l = gid & 63;
    const int l16 = l & 15, lq = l >> 4;

    const float* src = nullptr;
    int snc = 0, col = 0, k0 = 0;
    size_t dh = 0, dl = 0;
    if (gf < 640) {                        // WCAT: 40 tiles x 16 kc
        const int t = gf >> 4, kc = gf & 15;
        k0 = kc * 32 + lq * 8;
        const int c = t * 16 + l16;
        dh = OFF_WCAT_H + (size_t)gf * 512 + l * 8;
        dl = OFF_WCAT_L + (size_t)gf * 512 + l * 8;
        if (c < 256)      { src = W1a; snc = 256; col = c; }
        else if (c < 512) { src = Wfa; snc = 256; col = c - 256; }
        else if (c < 544) { src = Wb1; snc = 32;  col = c - 512; }
        else if (c < 576) { src = Wv1; snc = 32;  col = c - 544; }
        // c >= 576: pad tiles 36..39 -> zeros
    } else if (gf < 768) {                 // W1B: 16 tiles x 8 kc
        const int f = gf - 640;
        k0 = (f & 7) * 32 + lq * 8;
        col = (f >> 3) * 16 + l16;
        src = W1b; snc = 256;
        dh = OFF_W1B_H + (size_t)f * 512 + l * 8;
        dl = OFF_W1B_L + (size_t)f * 512 + l * 8;
    } else if (gf < 784) {                 // WFB: 2 tiles x 8 kc
        const int f = gf - 768;
        k0 = (f & 7) * 32 + lq * 8;
        col = (f >> 3) * 16 + l16;
        src = Wfb; snc = 32;
        dh = OFF_WFB_H + (size_t)f * 512 + l * 8;
        dl = OFF_WFB_L + (size_t)f * 512 + l * 8;
    } else if (gf < 788) {                 // TOK: 2 tiles x 2 kc (K=64)
        const int f = gf - 784;
        k0 = (f & 1) * 32 + lq * 8;
        col = (f >> 1) * 16 + l16;
        src = W_tok; snc = 32;
        dh = OFF_TOK_H + (size_t)f * 512 + l * 8;
        dl = OFF_TOK_L + (size_t)f * 512 + l * 8;
    } else {                               // YFC: 4 tiles x 1 kc (K=32)
        const int f = gf - 788;
        k0 = lq * 8;
        col = f * 16 + l16;
        src = W_yfc; snc = 64;
        dh = OFF_YFC_H + (size_t)f * 512 + l * 8;
        dl = OFF_YFC_L + (size_t)f * 512 + l * 8;
    }

    uint4 H = {0, 0, 0, 0}, L = {0, 0, 0, 0};
    if (src) {
        ush hv[8], lv[8];
        #pragma unroll
        for (int j = 0; j < 8; j++) {
            const float x = src[(size_t)(k0 + j) * snc + col];
            splitbf(x, hv[j], lv[j]);
        }
        H.x = (unsigned)hv[0] | ((unsigned)hv[1] << 16);
        H.y = (unsigned)hv[2] | ((unsigned)hv[3] << 16);
        H.z = (unsigned)hv[4] | ((unsigned)hv[5] << 16);
        H.w = (unsigned)hv[6] | ((unsigned)hv[7] << 16);
        L.x = (unsigned)lv[0] | ((unsigned)lv[1] << 16);
        L.y = (unsigned)lv[2] | ((unsigned)lv[3] << 16);
        L.z = (unsigned)lv[4] | ((unsigned)lv[5] << 16);
        L.w = (unsigned)lv[6] | ((unsigned)lv[7] << 16);
    }
    *(uint4*)(ws + dh) = H;
    *(uint4*)(ws + dl) = L;
}

// ---------------- main fused kernel (R8 verbatim) ----------------
__global__ __launch_bounds__(THREADS, 2) void xmix_mfma(
    const float* __restrict__ agent_qs,
    const float* __restrict__ states,
    const ush* __restrict__ ws,
    const float* __restrict__ b_tok, const float* __restrict__ b_yfc,
    const float* __restrict__ b1a,  const float* __restrict__ b1b,
    const float* __restrict__ bfa,  const float* __restrict__ bfb,
    const float* __restrict__ bb1,  const float* __restrict__ bv1,
    const float* __restrict__ Wv2,  const float* __restrict__ bv2,
    float* __restrict__ out)
{
    // BB phases:
    //  (1) Y-split bf16: hi [512 agent-rows][64f] @0 (64KB), lo @65536
    //  (2) H1-hi @0 (32KB), H1-lo @32768, HF-hi @65536, HF-lo @98304
    //  (3) w1 f32 [64][264] (a*33+e) @0 (67584), wf f32 [64][33] @67584,
    //      hidden [64][33] @76032, tprod @84480 (end 92928)
    __shared__ __align__(16) unsigned char BBs[131072];
    // SM: e-scratch (2KB/wave) -> b1 f32 [64][32] @0, v1 @8192
    __shared__ __align__(16) unsigned char SMs[16384];

    const int tid = threadIdx.x;
    const int wv = tid >> 6;          // wave 0..7
    const int l   = tid & 63;
    const int l16 = l & 15;
    const int lq  = l >> 4;
    const int base = blockIdx.x * TB;
    const f4 fzero = {0.f, 0.f, 0.f, 0.f};

    // ---- P1+P2: e = relu(s@W_tok+b) ; y = relu(e@W_yfc+b) -> Y-split in BB ----
    // States A-fragments come straight from global (register split) — no P0.
    {
        const ush* tokH = ws + OFF_TOK_H;
        const ush* tokL = ws + OFF_TOK_L;
        const ush* yfcH = ws + OFF_YFC_H;
        const ush* yfcL = ws + OFF_YFC_L;
        unsigned char* scr = &SMs[wv * 2048];   // e-split: hi[16][32] @0, lo @1024

        float btok[2];
        btok[0] = b_tok[l16]; btok[1] = b_tok[16 + l16];
        float byfc[4];
        #pragma unroll
        for (int n = 0; n < 4; n++) byfc[n] = b_yfc[n * 16 + l16];

        sh8 TBh[2][2], TBl[2][2];
        #pragma unroll
        for (int n = 0; n < 2; n++)
            #pragma unroll
            for (int kc = 0; kc < 2; kc++) {
                const int fo = ((n * 2 + kc) * 64 + l) * 8;   // fragment-major
                TBh[n][kc] = *(const sh8*)(tokH + fo);
                TBl[n][kc] = *(const sh8*)(tokL + fo);
            }
        sh8 YBh[4], YBl[4];
        #pragma unroll
        for (int n = 0; n < 4; n++) {
            const int fo = (n * 64 + l) * 8;
            YBh[n] = *(const sh8*)(yfcH + fo);
            YBl[n] = *(const sh8*)(yfcL + fo);
        }

        #pragma unroll
        for (int i = 0; i < 4; i++) {
            const int rt = wv * 4 + i;                 // e-row tile
            const int r = rt * 16 + l16;               // agent-row 0..511
            const float* srow = states + (size_t)(base + (r >> 3)) * 512 + (r & 7) * 64;
            f4 eacc[2] = {fzero, fzero};
            #pragma unroll
            for (int kc = 0; kc < 2; kc++) {
                const float4 v0 = *(const float4*)(srow + kc * 32 + lq * 8);
                const float4 v1 = *(const float4*)(srow + kc * 32 + lq * 8 + 4);
                sh8 Ah, Al;
                split8(v0, v1, Ah, Al);
                #pragma unroll
                for (int n = 0; n < 2; n++) {
                    eacc[n] = mfma(Ah, TBh[n][kc], eacc[n]);
                    eacc[n] = mfma(Ah, TBl[n][kc], eacc[n]);
                    eacc[n] = mfma(Al, TBh[n][kc], eacc[n]);
                }
            }
            // e -> per-wave scratch (split, swizzled)
            #pragma unroll
            for (int n = 0; n < 2; n++)
                #pragma unroll
                for (int j = 0; j < 4; j++) {
                    const float e = fmaxf(eacc[n][j] + btok[n], 0.f);
                    const unsigned sa = swS((unsigned)((lq * 4 + j) * 64 + (n * 16 + l16) * 2));
                    ush hh, ll; splitbf(e, hh, ll);
                    *(ush*)(scr + sa)        = hh;
                    *(ush*)(scr + 1024 + sa) = ll;
                }
            // P2: y-tile = e-tile @ W_yfc
            f4 yacc[4] = {fzero, fzero, fzero, fzero};
            {
                const unsigned sa = swS((unsigned)(l16 * 64 + lq * 16));
                const sh8 Ah = *(const sh8*)(scr + sa);
                const sh8 Al = *(const sh8*)(scr + 1024 + sa);
                #pragma unroll
                for (int n = 0; n < 4; n++) {
                    yacc[n] = mfma(Ah, YBh[n], yacc[n]);
                    yacc[n] = mfma(Ah, YBl[n], yacc[n]);
                    yacc[n] = mfma(Al, YBh[n], yacc[n]);
                }
            }
            // y -> Y-split planes
            #pragma unroll
            for (int n = 0; n < 4; n++)
                #pragma unroll
                for (int j = 0; j < 4; j++) {
                    const float y = fmaxf(yacc[n][j] + byfc[n], 0.f);
                    const int rr = rt * 16 + lq * 4 + j;
                    const int ss = rr >> 3, aa = rr & 7, ff = n * 16 + l16;
                    const unsigned sa = swY((unsigned)(ss * 1024 + (aa * 64 + ff) * 2));
                    ush hh, ll; splitbf(y, hh, ll);
                    *(ush*)(&BBs[sa])         = hh;
                    *(ush*)(&BBs[65536 + sa]) = ll;
                }
        }
    }

    // ---- P3: Y[64,512] @ Wcat[512,576] -> H1|HF|b1|v1 ----
    // 36 real tiles: waves 0-3 own 5 tiles (0..19), waves 4-7 own 4 (20..35).
    f4 acc3[4][5];
    #pragma unroll
    for (int m = 0; m < 4; m++)
        #pragma unroll
        for (int t = 0; t < 5; t++) acc3[m][t] = fzero;

    const ush* wcH = ws + OFF_WCAT_H;
    const ush* wcL = ws + OFF_WCAT_L;
    const int tb0 = (wv < 4) ? (wv * 5) : (20 + (wv - 4) * 4);
    int cb[5];
    #pragma unroll
    for (int t = 0; t < 5; t++) cb[t] = (tb0 + t) * 8192;   // tile*16kc*64l*8
    int rowb[4];
    #pragma unroll
    for (int m = 0; m < 4; m++) rowb[m] = (m * 16 + l16) * 1024;

    sh8 BhA[5], BlA[5], BhB[5], BlB[5];

#define LOADB(BH, BL, KC, N) { const int fo_ = (KC) * 512 + l * 8; \
    _Pragma("unroll") \
    for (int t = 0; t < N; t++) { \
        BH[t] = *(const sh8*)(wcH + cb[t] + fo_); \
        BL[t] = *(const sh8*)(wcL + cb[t] + fo_); \
    } }

#define DOMFMA(BH, BL, KC, N) { \
    const int ko_ = (KC) * 32 + lq * 8; \
    sh8 Ah_[4], Al_[4]; \
    _Pragma("unroll") \
    for (int m = 0; m < 4; m++) { \
        const unsigned sa_ = swY((unsigned)(rowb[m] + ko_ * 2)); \
        Ah_[m] = *(const sh8*)(&BBs[sa_]); \
        Al_[m] = *(const sh8*)(&BBs[65536 + sa_]); \
    } \
    _Pragma("unroll") \
    for (int m = 0; m < 4; m++) \
        _Pragma("unroll") \
        for (int t = 0; t < N; t++) acc3[m][t] = mfma(Ah_[m], BH[t], acc3[m][t]); \
    _Pragma("unroll") \
    for (int m = 0; m < 4; m++) \
        _Pragma("unroll") \
        for (int t = 0; t < N; t++) acc3[m][t] = mfma(Ah_[m], BL[t], acc3[m][t]); \
    _Pragma("unroll") \
    for (int m = 0; m < 4; m++) \
        _Pragma("unroll") \
        for (int t = 0; t < N; t++) acc3[m][t] = mfma(Al_[m], BH[t], acc3[m][t]); \
    }

    if (wv < 4) { LOADB(BhA, BlA, 0, 5); } else { LOADB(BhA, BlA, 0, 4); }
    __syncthreads();        // Y visible to all waves

    if (wv < 4) {
        #pragma unroll 1
        for (int kc2 = 0; kc2 < 8; kc2++) {
            LOADB(BhB, BlB, kc2 * 2 + 1, 5);
            DOMFMA(BhA, BlA, kc2 * 2, 5);
            LOADB(BhA, BlA, kc2 * 2 + 2, 5);   // kc=16 overshoot: in-bounds, unused
            DOMFMA(BhB, BlB, kc2 * 2 + 1, 5);
        }
    } else {
        #pragma unroll 1
        for (int kc2 = 0; kc2 < 8; kc2++) {
            LOADB(BhB, BlB, kc2 * 2 + 1, 4);
            DOMFMA(BhA, BlA, kc2 * 2, 4);
            LOADB(BhA, BlA, kc2 * 2 + 2, 4);   // overshoot safe
            DOMFMA(BhB, BlB, kc2 * 2 + 1, 4);
        }
    }
#undef LOADB
#undef DOMFMA

    // ---- P4 tile bases ----
    const ush* w1H = ws + OFF_W1B_H;
    const ush* w1L = ws + OFF_W1B_L;
    const ush* wfH = ws + OFF_WFB_H;
    const ush* wfL = ws + OFF_WFB_L;
    const int mw = wv & 3, nw = wv >> 2;     // wf tile (M,N)
    const int cb0 = (wv * 2 + 0) * 4096;     // W1b tile stride = 8kc*64l*8
    const int cb1 = (wv * 2 + 1) * 4096;
    const int cbw = nw * 4096;

    __syncthreads();   // all waves done reading Y

    // ---- P3 epilogue: acc3 -> H1-split / HF-split / b1 / v1 ----
#define EPIBODY(T_) { \
    const int gt = tb0 + (T_); \
    const int cg = gt * 16 + l16; \
    if (gt < 16) { \
        const float bias = b1a[cg]; \
        _Pragma("unroll") \
        for (int m = 0; m < 4; m++) \
            _Pragma("unroll") \
            for (int j = 0; j < 4; j++) { \
                const int row = m * 16 + lq * 4 + j; \
                const float h = fmaxf(acc3[m][T_][j] + bias, 0.f); \
                ush hh, ll; splitbf(h, hh, ll); \
                const unsigned sa = swH((unsigned)(row * 512 + cg * 2)); \
                *(ush*)(&BBs[sa])         = hh; \
                *(ush*)(&BBs[32768 + sa]) = ll; \
            } \
    } else if (gt < 32) { \
        const int c = cg - 256; \
        const float bias = bfa[c]; \
        _Pragma("unroll") \
        for (int m = 0; m < 4; m++) \
            _Pragma("unroll") \
            for (int j = 0; j < 4; j++) { \
                const int row = m * 16 + lq * 4 + j; \
                const float h = fmaxf(acc3[m][T_][j] + bias, 0.f); \
                ush hh, ll; splitbf(h, hh, ll); \
                const unsigned sa = swH((unsigned)(row * 512 + c * 2)); \
                *(ush*)(&BBs[65536 + sa]) = hh; \
                *(ush*)(&BBs[98304 + sa]) = ll; \
            } \
    } else if (gt < 34) { \
        const int c = cg - 512; \
        const float bias = bb1[c]; \
        _Pragma("unroll") \
        for (int m = 0; m < 4; m++) \
            _Pragma("unroll") \
            for (int j = 0; j < 4; j++) { \
                const int row = m * 16 + lq * 4 + j; \
                *(float*)(&SMs[(row * 32 + c) * 4]) = acc3[m][T_][j] + bias; \
            } \
    } else if (gt < 36) { \
        const int c = cg - 544; \
        const float bias = bv1[c]; \
        _Pragma("unroll") \
        for (int m = 0; m < 4; m++) \
            _Pragma("unroll") \
            for (int j = 0; j < 4; j++) { \
                const int row = m * 16 + lq * 4 + j; \
                *(float*)(&SMs[8192 + (row * 32 + c) * 4]) = \
                    fmaxf(acc3[m][T_][j] + bias, 0.f); \
            } \
    } }

    if (wv < 4) {
        EPIBODY(0) EPIBODY(1) EPIBODY(2) EPIBODY(3) EPIBODY(4)
    } else {
        EPIBODY(0) EPIBODY(1) EPIBODY(2) EPIBODY(3)
    }
#undef EPIBODY
    __syncthreads();

    // ---- P4: w1 = |H1@W1b + b1b| ; wf = |HF@Wfb + bfb| ----
    f4 acc4[4][2];
    #pragma unroll
    for (int m = 0; m < 4; m++) { acc4[m][0] = fzero; acc4[m][1] = fzero; }
    f4 accw = fzero;
    {
        #pragma unroll 2
        for (int kc = 0; kc < 8; kc++) {
            const int fo = kc * 512 + l * 8;
            const int ko = kc * 32 + lq * 8;
            const sh8 B0h = *(const sh8*)(w1H + cb0 + fo);
            const sh8 B0l = *(const sh8*)(w1L + cb0 + fo);
            const sh8 B1h = *(const sh8*)(w1H + cb1 + fo);
            const sh8 B1l = *(const sh8*)(w1L + cb1 + fo);
            const sh8 Wh  = *(const sh8*)(wfH + cbw + fo);
            const sh8 Wl  = *(const sh8*)(wfL + cbw + fo);
            sh8 Ah[4], Al[4];
            #pragma unroll
            for (int m = 0; m < 4; m++) {
                const unsigned sa = swH((unsigned)((m * 16 + l16) * 512 + ko * 2));
                Ah[m] = *(const sh8*)(&BBs[sa]);
                Al[m] = *(const sh8*)(&BBs[32768 + sa]);
            }
            const unsigned saw = swH((unsigned)((mw * 16 + l16) * 512 + ko * 2));
            const sh8 Awh = *(const sh8*)(&BBs[65536 + saw]);
            const sh8 Awl = *(const sh8*)(&BBs[98304 + saw]);
            #pragma unroll
            for (int m = 0; m < 4; m++) {
                acc4[m][0] = mfma(Ah[m], B0h, acc4[m][0]);
                acc4[m][1] = mfma(Ah[m], B1h, acc4[m][1]);
            }
            accw = mfma(Awh, Wh, accw);
            #pragma unroll
            for (int m = 0; m < 4; m++) {
                acc4[m][0] = mfma(Ah[m], B0l, acc4[m][0]);
                acc4[m][1] = mfma(Ah[m], B1l, acc4[m][1]);
            }
            accw = mfma(Awh, Wl, accw);
            #pragma unroll
            for (int m = 0; m < 4; m++) {
                acc4[m][0] = mfma(Al[m], B0h, acc4[m][0]);
                acc4[m][1] = mfma(Al[m], B1h, acc4[m][1]);
            }
            accw = mfma(Awl, Wh, accw);
        }
    }
    __syncthreads();   // H1/HF consumed

    // w1/wf -> f32 LDS (de-conflicted: w1 [64][264] a*33+e, wf [64][33])
    {
        #pragma unroll
        for (int t = 0; t < 2; t++) {
            const int col = (wv * 2 + t) * 16 + l16;
            const int a = col >> 5, e = col & 31;
            const float bias = b1b[col];
            #pragma unroll
            for (int m = 0; m < 4; m++)
                #pragma unroll
                for (int j = 0; j < 4; j++) {
                    const int row = m * 16 + lq * 4 + j;
                    *(float*)(&BBs[(row * 264 + a * 33 + e) * 4]) =
                        fabsf(acc4[m][t][j] + bias);
                }
        }
        {
            const int col = nw * 16 + l16;
            const float bias = bfb[col];
            #pragma unroll
            for (int j = 0; j < 4; j++) {
                const int row = mw * 16 + lq * 4 + j;
                *(float*)(&BBs[67584 + (row * 33 + col) * 4]) =
                    fabsf(accw[j] + bias);
            }
        }
    }
    __syncthreads();

    // ---- P5: epilogue (elu, delu, q_tot, grad) ----
    {
        const int s = tid >> 3, li = tid & 7;
        const int b = base + s;
        float q[8];
        #pragma unroll
        for (int a = 0; a < 8; a++) q[a] = agent_qs[(size_t)b * 8 + a];
        const float* w1p = (const float*)(&BBs[0]);        // [64][264], a*33+e
        const float* wfp = (const float*)(&BBs[67584]);    // [64][33]
        const float* b1p = (const float*)(&SMs[0]);        // [64][32]
        float* hidp = (float*)(&BBs[76032]);               // [64][33]
        float* tpp  = (float*)(&BBs[84480]);               // [64][33]
        #pragma unroll
        for (int ii = 0; ii < 4; ii++) {
            const int e = li + 8 * ii;
            float z = b1p[s * 32 + e];
            #pragma unroll
            for (int a = 0; a < 8; a++) z = fmaf(q[a], w1p[s * 264 + a * 33 + e], z);
            const float h = (z > 0.f) ? z : (expf(z) - 1.f);   // elu
            const float d = (h < 0.f) ? expf(h) : 1.f;          // delu of elu OUTPUT (ref!)
            hidp[s * 33 + e] = h;
            tpp[s * 33 + e] = d * wfp[s * 33 + e];
        }
    }
    __syncthreads();
    {
        const float* w1p = (const float*)(&BBs[0]);
        const float* wfp = (const float*)(&BBs[67584]);
        const float* v1p = (const float*)(&SMs[8192]);
        const float* hidp = (const float*)(&BBs[76032]);
        const float* tpp  = (const float*)(&BBs[84480]);
        {
            const int s = tid >> 3, a = tid & 7;
            const int b = base + s;
            float g = 0.f;
            #pragma unroll
            for (int e = 0; e < 32; e++)
                g = fmaf(w1p[s * 264 + a * 33 + e], tpp[s * 33 + e], g);
            out[NB + (size_t)b * 8 + a] = g;
        }
        if (tid < 64) {
            const int s2 = tid, b2 = base + s2;
            float v = bv2[0];
            #pragma unroll
            for (int e = 0; e < 32; e++) v = fmaf(v1p[s2 * 32 + e], Wv2[e], v);
            float qt = v;
            #pragma unroll
            for (int e = 0; e < 32; e++)
                qt = fmaf(hidp[s2 * 33 + e], wfp[s2 * 33 + e], qt);
            out[b2] = qt;
        }
    }
}

extern "C" void kernel_launch(void* const* d_in, const int* in_sizes, int n_in,
                              void* d_out, int out_size, void* d_ws, size_t ws_size,
                              hipStream_t stream) {
    const float* agent_qs = (const float*)d_in[0];
    // d_in[1] = hist (unused by reference)
    const float* states   = (const float*)d_in[2];
    // d_in[3] = obs (unused by reference)
    const float* W_tok = (const float*)d_in[4];
    const float* b_tok = (const float*)d_in[5];
    const float* W_yfc = (const float*)d_in[6];
    const float* b_yfc = (const float*)d_in[7];
    const float* W1a   = (const float*)d_in[8];
    const float* b1a   = (const float*)d_in[9];
    const float* W1b   = (const float*)d_in[10];
    const float* b1b   = (const float*)d_in[11];
    const float* Wfa   = (const float*)d_in[12];
    const float* bfa   = (const float*)d_in[13];
    const float* Wfb   = (const float*)d_in[14];
    const float* bfb   = (const float*)d_in[15];
    const float* Wb1   = (const float*)d_in[16];
    const float* bb1   = (const float*)d_in[17];
    const float* Wv1   = (const float*)d_in[18];
    const float* bv1   = (const float*)d_in[19];
    const float* Wv2   = (const float*)d_in[20];
    const float* bv2   = (const float*)d_in[21];
    float* out = (float*)d_out;
    ush* ws = (ush*)d_ws;   // needs 1,622,016 B

    xmix_prep<<<99, 512, 0, stream>>>(W_tok, W_yfc, W1a, W1b, Wfa, Wfb, Wb1, Wv1, ws);
    xmix_mfma<<<NBLOCKS, THREADS, 0, stream>>>(
        agent_qs, states, ws, b_tok, b_yfc, b1a, b1b, bfa, bfb,
        bb1, bv1, Wv2, bv2, out);
}